// Round 15
// baseline (317.719 us; speedup 1.0000x reference)
//
#include <hip/hip_runtime.h>
#include <hip/hip_bf16.h>

#define EPS_RMS 1.1920929e-07f

constexpr int B_ = 2, S_ = 2048, D_ = 1024, H_ = 16, HD_ = 64, SD_ = 64;
constexpr int M_ = B_ * S_;      // 4096 rows
constexpr int D3_ = 3 * D_;      // 3072
constexpr int NT2_ = 512 * 512;  // partial-buffer stride (blocks x threads)

using short8 = __attribute__((ext_vector_type(8))) short;
using f32x4  = __attribute__((ext_vector_type(4))) float;
using f32x16 = __attribute__((ext_vector_type(16))) float;
typedef int v2i __attribute__((ext_vector_type(2)));

static __device__ __forceinline__ ushort f2bf(float x) {
  __hip_bfloat16 h = __float2bfloat16(x);
  return *reinterpret_cast<ushort*>(&h);
}
static __device__ __forceinline__ float bf2f(ushort u) {
  __hip_bfloat16 h;
  *reinterpret_cast<ushort*>(&h) = u;
  return __bfloat162float(h);
}
static __device__ __forceinline__ unsigned pk2(float lo, float hi) {
  return (unsigned)f2bf(lo) | ((unsigned)f2bf(hi) << 16);
}
// v_permlane32_swap_b32: ret.x = [a.lo, b.lo], ret.y = [a.hi, b.hi]
static __device__ __forceinline__ v2i swap32(int a, int b) {
  return __builtin_amdgcn_permlane32_swap(a, b, false, false);
}
struct alignas(8) bf4 { ushort a, b, c, d; };

// async global->LDS, 16B per lane; LDS dest = wave-uniform base + lane*16
static __device__ __forceinline__ void gload16(const ushort* g, ushort* l) {
  __builtin_amdgcn_global_load_lds(
      (const __attribute__((address_space(1))) unsigned int*)g,
      (__attribute__((address_space(3))) unsigned int*)l, 16, 0, 0);
}

// ---------------- FiLM modulation ----------------
__global__ void film_kernel(const float* __restrict__ state,
                            const float* __restrict__ w_sm,
                            const float* __restrict__ gamma,
                            const float* __restrict__ beta,
                            float* __restrict__ fg, float* __restrict__ fb) {
  int c = blockIdx.x * 256 + threadIdx.x;   // 0..2047
  int b = blockIdx.y;
  float acc = 0.f;
#pragma unroll 8
  for (int k = 0; k < SD_; ++k)
    acc += state[b * SD_ + k] * w_sm[k * (2 * D_) + c];
  if (c < D_) fg[b * D_ + c] = gamma[c] * (1.f + acc);
  else        fb[b * D_ + (c - D_)] = beta[c - D_] + acc;
}

// ---------------- RMSNorm + FiLM -> bf16 ----------------
__global__ __launch_bounds__(256) void rmsnorm_film_kernel(
    const float* __restrict__ X, const float* __restrict__ nw,
    const float* __restrict__ fg, const float* __restrict__ fb,
    ushort* __restrict__ Hout) {
  int row = blockIdx.x;            // 0..4095
  int b = row / S_;
  int t = threadIdx.x;
  const float4* x4 = (const float4*)(X + (size_t)row * D_);
  float4 xv = x4[t];
  float ss = xv.x * xv.x + xv.y * xv.y + xv.z * xv.z + xv.w * xv.w;
#pragma unroll
  for (int off = 32; off >= 1; off >>= 1) ss += __shfl_xor(ss, off);
  __shared__ float red[4];
  if ((t & 63) == 0) red[t >> 6] = ss;
  __syncthreads();
  float tot = red[0] + red[1] + red[2] + red[3];
  float scale = rsqrtf(tot / (float)D_ + EPS_RMS);
  int d = t * 4;
  const float4 nw4 = *(const float4*)(nw + d);
  const float4 g4  = *(const float4*)(fg + b * D_ + d);
  const float4 b4  = *(const float4*)(fb + b * D_ + d);
  bf4 hv;
  hv.a = f2bf(xv.x * scale * nw4.x * g4.x + b4.x);
  hv.b = f2bf(xv.y * scale * nw4.y * g4.y + b4.y);
  hv.c = f2bf(xv.z * scale * nw4.z * g4.z + b4.z);
  hv.d = f2bf(xv.w * scale * nw4.w * g4.w + b4.w);
  *(bf4*)(Hout + (size_t)row * D_ + d) = hv;
}

// ---------------- weight transpose + f32->bf16: Wt[n][k] = bf16(W[k][n]) ----------------
__global__ __launch_bounds__(256) void transpose_bf16(
    const float* __restrict__ W, ushort* __restrict__ Wt, int K, int N) {
  __shared__ float tile[32][33];
  int n0 = blockIdx.x * 32, k0 = blockIdx.y * 32;
  int t = threadIdx.x;
  int c = t & 31, r = t >> 5;
#pragma unroll
  for (int p = 0; p < 4; ++p)
    tile[r + 8 * p][c] = W[(size_t)(k0 + r + 8 * p) * N + n0 + c];
  __syncthreads();
#pragma unroll
  for (int p = 0; p < 4; ++p)
    Wt[(size_t)(n0 + r + 8 * p) * K + k0 + c] = f2bf(tile[c][r + 8 * p]);
}

// dual variant with independent dims: z=0 (W0,K0,N0)->T0, z=1 (W1,K1,N1)->T1.
__global__ __launch_bounds__(256) void transpose_bf16_dual2(
    const float* __restrict__ W0, ushort* __restrict__ T0, int K0, int N0,
    const float* __restrict__ W1, ushort* __restrict__ T1, int K1, int N1) {
  const float* W = blockIdx.z ? W1 : W0;
  ushort* Wt = blockIdx.z ? T1 : T0;
  int K = blockIdx.z ? K1 : K0;
  int N = blockIdx.z ? N1 : N0;
  int n0 = blockIdx.x * 32, k0 = blockIdx.y * 32;
  if (n0 >= N || k0 >= K) return;
  __shared__ float tile[32][33];
  int t = threadIdx.x;
  int c = t & 31, r = t >> 5;
#pragma unroll
  for (int p = 0; p < 4; ++p)
    tile[r + 8 * p][c] = W[(size_t)(k0 + r + 8 * p) * N + n0 + c];
  __syncthreads();
#pragma unroll
  for (int p = 0; p < 4; ++p)
    Wt[(size_t)(n0 + r + 8 * p) * K + k0 + c] = f2bf(tile[c][r + 8 * p]);
}

// ---------------- MFMA micro-tile compute: one BK=64 K-tile ----------------
static __device__ __forceinline__ void mfma_tile(
    const char* Au, const char* Bu, f32x4 (&acc)[4][4],
    int l15, int l4, int swz, int wr, int wc) {
#pragma unroll
  for (int kk = 0; kk < 2; ++kk) {
    int tslot = ((kk * 4 + l4) ^ swz) << 4;
    short8 a[4], b[4];
#pragma unroll
    for (int i = 0; i < 4; ++i) {
      int arow = wr * 64 + i * 16 + l15;
      int brow = wc * 64 + i * 16 + l15;
      a[i] = *(const short8*)(Au + arow * 128 + tslot);
      b[i] = *(const short8*)(Bu + brow * 128 + tslot);
    }
#pragma unroll
    for (int m = 0; m < 4; ++m)
#pragma unroll
      for (int n = 0; n < 4; ++n)
        acc[m][n] = __builtin_amdgcn_mfma_f32_16x16x32_bf16(a[m], b[n], acc[m][n], 0, 0, 0);
  }
}

// block swizzle helper: XCD-chunked 2D (GROUP_M=8, bn-fast)
static __device__ __forceinline__ void block_swizzle(int bid, int M, int N,
                                                     int& bm, int& bn) {
  int nbn = N >> 7;
  int nb  = nbn * (M >> 7);
  int qx  = nb >> 3;
  int lin = (bid & 7) * qx + (bid >> 3);
  int grp = lin / (nbn << 3), rem = lin % (nbn << 3);
  bm = ((grp << 3) + (rem & 7)) << 7;
  bn = (rem >> 3) << 7;
}

// ---------------- bf16 MFMA GEMM: C = A(MxK) @ Bt(NxK)^T ----------------
// EPI: 3 = Res+acc->f32; 4 = qkv split (Q/K bf16 + V^T); 5 = Res+acc->f32 +
//      fused column-sum atomicAdd (sums the WRITTEN value, aliasing-safe).
template<int EPI>
__global__ __launch_bounds__(256, 4) void gemm_mfma(
    const ushort* __restrict__ A, const ushort* __restrict__ Bt,
    const float* __restrict__ Res,
    float* __restrict__ Cf, ushort* __restrict__ Cb, ushort* __restrict__ VtP,
    float* __restrict__ Csum,
    int M, int N, int K) {
  __shared__ ushort smem[16384];       // 32KB: A [0,8192) ushorts, B [8192,16384)
  char* Au = (char*)smem;
  char* Bu = (char*)(smem + 8192);
  int t = threadIdx.x;
  int bm, bn;
  block_swizzle(blockIdx.x, M, N, bm, bn);

  int lane = t & 63, wid = t >> 6;
  int wr = wid >> 1, wc = wid & 1;
  int l15 = lane & 15, l4 = lane >> 4;
  int swz = l15 & 7;

  const ushort* gA[4];
  const ushort* gB[4];
  ushort* lA[4];
  ushort* lB[4];
#pragma unroll
  for (int p = 0; p < 4; ++p) {
    int seg = p * 4 + wid;
    int flat = seg * 64 + lane;
    int row = flat >> 3, sl = flat & 7;
    int gc = ((sl ^ (row & 7)) << 3);    // inverse-swizzled source column
    gA[p] = A  + (size_t)(bm + row) * K + gc;
    gB[p] = Bt + (size_t)(bn + row) * K + gc;
    lA[p] = smem + seg * 512;            // wave-uniform base
    lB[p] = smem + 8192 + seg * 512;
  }

  f32x4 acc[4][4];
#pragma unroll
  for (int m = 0; m < 4; ++m)
#pragma unroll
    for (int n = 0; n < 4; ++n) acc[m][n] = (f32x4){0.f, 0.f, 0.f, 0.f};

  int nk = K >> 6;
  for (int kt = 0; kt < nk; ++kt) {
    __syncthreads();
#pragma unroll
    for (int p = 0; p < 4; ++p) {
      gload16(gA[p], lA[p]);
      gload16(gB[p], lB[p]);
      gA[p] += 64; gB[p] += 64;
    }
    __syncthreads();
    mfma_tile(Au, Bu, acc, l15, l4, swz, wr, wc);
  }

  if constexpr (EPI == 3 || EPI == 5) {
#pragma unroll
    for (int n = 0; n < 4; ++n) {
      int col = bn + wc * 64 + n * 16 + l15;
      float s = 0.f;
#pragma unroll
      for (int m = 0; m < 4; ++m) {
        int row0 = bm + wr * 64 + m * 16 + l4 * 4;
#pragma unroll
        for (int j = 0; j < 4; ++j) {
          size_t idx = (size_t)(row0 + j) * (size_t)N + col;
          float outv = Res[idx] + acc[m][n][j];
          Cf[idx] = outv;
          s += outv;                     // sum the written value (alias-safe)
        }
      }
      if constexpr (EPI == 5)
        atomicAdd(&Csum[(bm >> 11) * 1024 + col], s);
    }
  } else {
    // LDS-staged coalesced bf16 epilogue (EPI == 4)
    __syncthreads();
    ushort* Es = smem;                   // 128x128 bf16 = 32KB
    bool vblk = (bn >= 2048);
#pragma unroll
    for (int m = 0; m < 4; ++m)
#pragma unroll
      for (int n = 0; n < 4; ++n) {
        int rb0 = wr * 64 + m * 16 + l4 * 4;
        int c   = wc * 64 + n * 16 + l15;
#pragma unroll
        for (int j = 0; j < 4; ++j) {
          float v = acc[m][n][j];
          int r = rb0 + j;
          if (vblk) Es[c * 128 + (r ^ ((c & 15) << 3))] = f2bf(v);  // transposed + XOR perm
          else      Es[r * 128 + c] = f2bf(v);
        }
      }
    __syncthreads();
    if (vblk) {
#pragma unroll
      for (int p = 0; p < 8; ++p) {
        int flat = p * 256 + t;
        int c = flat >> 4, r8 = (flat & 15) * 8;
        int vc = bn - 2048 + c, hh = vc >> 6, dd = vc & 63;
        int bbv = bm >> 11, s0 = (bm & 2047) + r8;
        *(short8*)(VtP + ((((size_t)bbv * 16 + hh) * 64 + dd) << 11) + s0) =
            *(const short8*)&Es[c * 128 + (r8 ^ ((c & 15) << 3))];
      }
    } else {
#pragma unroll
      for (int p = 0; p < 8; ++p) {
        int flat = p * 256 + t;
        int r = flat >> 4, c8 = (flat & 15) * 8;
        *(short8*)(Cb + (size_t)(bm + r) * N + bn + c8) = *(const short8*)&Es[r * 128 + c8];
      }
    }
  }
}

// ---------------- fused dual GEMM: Cb = silu(A@Gt^T) * (A@Ut^T), bf16 ----------------
// NOTE: (256,2) required — ag+au accumulators alone are 128 VGPRs (R10 spill lesson).
__global__ __launch_bounds__(256, 2) void gemm_dual(
    const ushort* __restrict__ A, const ushort* __restrict__ Gt,
    const ushort* __restrict__ Ut, ushort* __restrict__ Cb,
    int M, int N, int K) {
  __shared__ ushort smem[24576];       // 48KB: A, Bg, Bu tiles
  char* Au = (char*)smem;
  char* Gu = (char*)(smem + 8192);
  char* Uu = (char*)(smem + 16384);
  int t = threadIdx.x;
  int bm, bn;
  block_swizzle(blockIdx.x, M, N, bm, bn);

  int lane = t & 63, wid = t >> 6;
  int wr = wid >> 1, wc = wid & 1;
  int l15 = lane & 15, l4 = lane >> 4;
  int swz = l15 & 7;

  const ushort* gA[4]; const ushort* gG[4]; const ushort* gU[4];
  ushort* lA[4]; ushort* lG[4]; ushort* lU[4];
#pragma unroll
  for (int p = 0; p < 4; ++p) {
    int seg = p * 4 + wid;
    int flat = seg * 64 + lane;
    int row = flat >> 3, sl = flat & 7;
    int gc = ((sl ^ (row & 7)) << 3);
    gA[p] = A  + (size_t)(bm + row) * K + gc;
    gG[p] = Gt + (size_t)(bn + row) * K + gc;
    gU[p] = Ut + (size_t)(bn + row) * K + gc;
    lA[p] = smem + seg * 512;
    lG[p] = smem + 8192 + seg * 512;
    lU[p] = smem + 16384 + seg * 512;
  }

  f32x4 ag[4][4], au[4][4];
#pragma unroll
  for (int m = 0; m < 4; ++m)
#pragma unroll
    for (int n = 0; n < 4; ++n) {
      ag[m][n] = (f32x4){0.f, 0.f, 0.f, 0.f};
      au[m][n] = (f32x4){0.f, 0.f, 0.f, 0.f};
    }

  int nk = K >> 6;
  for (int kt = 0; kt < nk; ++kt) {
    __syncthreads();
#pragma unroll
    for (int p = 0; p < 4; ++p) {
      gload16(gA[p], lA[p]);
      gload16(gG[p], lG[p]);
      gload16(gU[p], lU[p]);
      gA[p] += 64; gG[p] += 64; gU[p] += 64;
    }
    __syncthreads();
#pragma unroll
    for (int kk = 0; kk < 2; ++kk) {
      int tslot = ((kk * 4 + l4) ^ swz) << 4;
      short8 a[4], bg[4], bu[4];
#pragma unroll
      for (int i = 0; i < 4; ++i) {
        int arow = wr * 64 + i * 16 + l15;
        int brow = wc * 64 + i * 16 + l15;
        a[i]  = *(const short8*)(Au + arow * 128 + tslot);
        bg[i] = *(const short8*)(Gu + brow * 128 + tslot);
        bu[i] = *(const short8*)(Uu + brow * 128 + tslot);
      }
#pragma unroll
      for (int m = 0; m < 4; ++m)
#pragma unroll
        for (int n = 0; n < 4; ++n) {
          ag[m][n] = __builtin_amdgcn_mfma_f32_16x16x32_bf16(a[m], bg[n], ag[m][n], 0, 0, 0);
          au[m][n] = __builtin_amdgcn_mfma_f32_16x16x32_bf16(a[m], bu[n], au[m][n], 0, 0, 0);
        }
    }
  }

  __syncthreads();
  ushort* Es = smem;
#pragma unroll
  for (int m = 0; m < 4; ++m)
#pragma unroll
    for (int n = 0; n < 4; ++n) {
      int rb0 = wr * 64 + m * 16 + l4 * 4;
      int c   = wc * 64 + n * 16 + l15;
#pragma unroll
      for (int j = 0; j < 4; ++j) {
        float gv = ag[m][n][j];
        float v = gv / (1.f + __expf(-gv)) * au[m][n][j];
        Es[(rb0 + j) * 128 + c] = f2bf(v);
      }
    }
  __syncthreads();
#pragma unroll
  for (int p = 0; p < 8; ++p) {
    int flat = p * 256 + t;
    int r = flat >> 4, c8 = (flat & 15) * 8;
    *(short8*)(Cb + (size_t)(bm + r) * N + bn + c8) = *(const short8*)&Es[r * 128 + c8];
  }
}

// ---------------- MFMA causal flash attention, k-parity split ----------------
__global__ __launch_bounds__(512, 4) void attn_mfma_kernel(
    const ushort* __restrict__ qkv,   // [B*S][3072] bf16 (Q at 0, K at 1024)
    const ushort* __restrict__ Vt,    // [B*H][64][2048] bf16
    unsigned* __restrict__ PO,        // [16][NT2] packed bf16x2 O-partials
    float* __restrict__ PM, float* __restrict__ PL) {  // [NT2] each
  __shared__ ushort lds[16384];       // 2 x (K 4096 + V 4096)
  const float SL2 = 0.125f * 1.44269504f;   // scale * log2(e)
  int t = threadIdx.x;
  int x = blockIdx.x;
  int lin = ((x & 7) << 6) + (x >> 3);   // XCD chunks of 64 blocks
  int kh = lin & 1;
  int pp = (lin >> 1) & 7;
  int hb = lin >> 4;                     // 0..31
  int h = hb & 15, bb = hb >> 4;
  int lane = t & 63, wv = t >> 6;        // wv 0..7
  int qi = wv >> 2, wsub = wv & 3;
  int qt = qi ? (15 - pp) : pp;
  int q0 = qt * 128;
  int l31 = lane & 31, g = lane >> 5;

  int qrow = q0 + wsub * 32 + l31;
  const ushort* qrow_ptr = qkv + (size_t)(bb * S_ + qrow) * 3072 + h * 64;
  short8 qf[4];
#pragma unroll
  for (int s = 0; s < 4; ++s) qf[s] = *(const short8*)(qrow_ptr + s * 16 + g * 8);

  f32x16 accO[2];
#pragma unroll
  for (int u = 0; u < 2; ++u)
#pragma unroll
    for (int r = 0; r < 16; ++r) accO[u][r] = 0.f;
  float m = -INFINITY, l = 0.f;
  int qg = qrow;
  int qmin = q0 + wsub * 32, qmax = qmin + 31;
  int ntpair = 2 * (16 - pp);            // full staged span of the pair
  int ntk = (ntpair - kh + 1) >> 1;      // this block's tile count (parity kh)

  const ushort* kbase = qkv + (size_t)(bb * S_) * 3072 + 1024 + h * 64;
  const ushort* vbase = Vt + ((size_t)(bb * 16 + h) * 64) * 2048;

  int srow = t >> 3, sslot = t & 7;
  int soff = srow * 64 + ((sslot ^ (srow & 7)) << 3);
  const ushort* kg0 = kbase + (size_t)srow * 3072 + sslot * 8;
  const ushort* vg0 = vbase + (size_t)srow * 2048 + sslot * 8;

  // prologue: stage tile kh into buf 0
  *(short8*)&lds[soff] = *(const short8*)(kg0 + (size_t)kh * (64 * 3072));
  *(short8*)&lds[4096 + soff] = *(const short8*)(vg0 + kh * 64);
  __syncthreads();

  for (int i2 = 0; i2 < ntk; ++i2) {
    int cur = i2 & 1;
    int kti = 2 * i2 + kh;
    int kt = kti << 6;
    bool pf = (i2 + 1 < ntk);
    short8 rk, rv;
    if (pf) {                            // issue next-parity-tile loads early
      rk = *(const short8*)(kg0 + (size_t)(kti + 2) * (64 * 3072));
      rv = *(const short8*)(vg0 + (kti + 2) * 64);
    }
    if (kt <= qmax) {
      const ushort* Kb = lds + cur * 8192;
      const ushort* Vb = Kb + 4096;

      f32x16 accT[2];
#pragma unroll
      for (int t2 = 0; t2 < 2; ++t2)
#pragma unroll
        for (int r = 0; r < 16; ++r) accT[t2][r] = 0.f;
      __builtin_amdgcn_s_setprio(1);
#pragma unroll
      for (int t2 = 0; t2 < 2; ++t2) {
        int key = 32 * t2 + l31;
#pragma unroll
        for (int s = 0; s < 4; ++s) {
          short8 kf = *(const short8*)&Kb[key * 64 + (((2 * s + g) ^ (key & 7)) << 3)];
          accT[t2] = __builtin_amdgcn_mfma_f32_32x32x16_bf16(kf, qf[s], accT[t2], 0, 0, 0);
        }
      }
      __builtin_amdgcn_s_setprio(0);

      bool need_mask = (kt + 63 > qmin);
      float p_[2][16];
      float pmax = -INFINITY;
#pragma unroll
      for (int t2 = 0; t2 < 2; ++t2)
#pragma unroll
        for (int r = 0; r < 16; ++r) {
          float v = accT[t2][r] * SL2;
          if (need_mask) {
            int key = kt + 32 * t2 + (r & 3) + 8 * (r >> 2) + 4 * g;
            if (key > qg) v = -INFINITY;
          }
          p_[t2][r] = v;
          pmax = fmaxf(pmax, v);
        }
      {
        v2i pm = swap32(__float_as_int(pmax), __float_as_int(pmax));
        pmax = fmaxf(pmax, __int_as_float(g ? pm.x : pm.y));
      }

      if (__any(pmax > m + 11.5f)) {     // defer-max
        float mnew = fmaxf(m, pmax);
        float corr = exp2f(m - mnew);
        m = mnew;
        l *= corr;
        float cr[16];
#pragma unroll
        for (int r = 0; r < 16; ++r) cr[r] = __shfl(corr, (r & 3) + 8 * (r >> 2) + 4 * g);
#pragma unroll
        for (int r = 0; r < 16; ++r) { accO[0][r] *= cr[r]; accO[1][r] *= cr[r]; }
      }
      float psum = 0.f;
#pragma unroll
      for (int t2 = 0; t2 < 2; ++t2)
#pragma unroll
        for (int r = 0; r < 16; ++r) {
          float e = exp2f(p_[t2][r] - m);
          p_[t2][r] = e;
          psum += e;
        }
      {
        v2i ps = swap32(__float_as_int(psum), __float_as_int(psum));
        psum += __int_as_float(g ? ps.x : ps.y);
      }
      l += psum;

#pragma unroll
      for (int s = 0; s < 4; ++s) {
        int ca = 2 * s, cb2 = 2 * s + 1;
        int ta = ca >> 2, ra = (ca & 3) * 4;
        int tb = cb2 >> 2, rbq = (cb2 & 3) * 4;
        int w0a = (int)pk2(p_[ta][ra], p_[ta][ra + 1]);
        int w1a = (int)pk2(p_[ta][ra + 2], p_[ta][ra + 3]);
        int w0b = (int)pk2(p_[tb][rbq], p_[tb][rbq + 1]);
        int w1b = (int)pk2(p_[tb][rbq + 2], p_[tb][rbq + 3]);
        v2i r0 = swap32(w0a, w0b);
        v2i r1 = swap32(w1a, w1b);
        union { int u[4]; short8 s8; } pa;
        pa.u[0] = r0.x;
        pa.u[1] = r1.x;
        pa.u[2] = r0.y;
        pa.u[3] = r1.y;
        __builtin_amdgcn_s_setprio(1);
#pragma unroll
        for (int u = 0; u < 2; ++u) {
          int d = 32 * u + l31;
          short8 vf = *(const short8*)&Vb[d * 64 + (((2 * s + g) ^ (d & 7)) << 3)];
          accO[u] = __builtin_amdgcn_mfma_f32_32x32x16_bf16(pa.s8, vf, accO[u], 0, 0, 0);
        }
        __builtin_amdgcn_s_setprio(0);
      }
    }
    if (pf) {                            // write prefetched tile into other buffer
      ushort* dst = lds + (cur ^ 1) * 8192;
      *(short8*)&dst[soff] = rk;
      *(short8*)&dst[4096 + soff] = rv;
    }
    __syncthreads();
  }

  // dump partials (coalesced SoA; O as packed bf16 pairs)
  size_t base = (size_t)lin * 512 + t;
#pragma unroll
  for (int r = 0; r < 16; ++r)
    PO[(size_t)r * NT2_ + base] = pk2(accO[0][r], accO[1][r]);
  PM[base] = m;
  PL[base] = l;
}

// ---------------- attention partial merge (kh=0 + kh=1) ----------------
__global__ __launch_bounds__(512, 2) void attn_merge_kernel(
    const unsigned* __restrict__ PO, const float* __restrict__ PM,
    const float* __restrict__ PL, ushort* __restrict__ AO) {
  __shared__ ushort lds[16384];
  int t = threadIdx.x;
  int xb = blockIdx.x;
  int lin2 = ((xb & 7) << 5) + (xb >> 3);   // XCD chunks of 32
  int pp = lin2 & 7;
  int hb = lin2 >> 3;
  int h = hb & 15, bb = hb >> 4;
  int lane = t & 63, wv = t >> 6;
  int l31 = lane & 31, g = lane >> 5;

  size_t p0 = ((size_t)((hb << 4) | (pp << 1)) * 512) + t;
  size_t p1 = p0 + 512;
  float m0 = PM[p0], l0 = PL[p0];
  float m1 = PM[p1], l1 = PL[p1];
  float mn = fmaxf(m0, m1);
  float c0 = exp2f(m0 - mn), c1 = exp2f(m1 - mn);   // m1=-inf -> c1=0
  float linv = 1.f / (l0 * c0 + l1 * c1);

  float cr0[16], cr1[16], lr[16];
#pragma unroll
  for (int r = 0; r < 16; ++r) {
    int src = (r & 3) + 8 * (r >> 2) + 4 * g;
    cr0[r] = __shfl(c0, src);
    cr1[r] = __shfl(c1, src);
    lr[r]  = __shfl(linv, src);
  }
#pragma unroll
  for (int r = 0; r < 16; ++r) {
    unsigned u0 = PO[(size_t)r * NT2_ + p0];
    unsigned u1 = PO[(size_t)r * NT2_ + p1];
    float a0 = bf2f((ushort)(u0 & 0xffff)), b0 = bf2f((ushort)(u0 >> 16));
    float a1 = bf2f((ushort)(u1 & 0xffff)), b1 = bf2f((ushort)(u1 >> 16));
    int row = wv * 32 + (r & 3) + 8 * (r >> 2) + 4 * g;
    lds[row * 64 + l31]      = f2bf((a0 * cr0[r] + a1 * cr1[r]) * lr[r]);
    lds[row * 64 + 32 + l31] = f2bf((b0 * cr0[r] + b1 * cr1[r]) * lr[r]);
  }
  __syncthreads();
#pragma unroll
  for (int p = 0; p < 4; ++p) {
    int flat = p * 512 + t;              // 0..2047
    int row = flat >> 3, slot = flat & 7;
    int qto = (row < 128) ? pp : (15 - pp);
    int grow = row & 127;
    *(short8*)(AO + (size_t)(bb * S_ + qto * 128 + grow) * 1024 + h * 64 + slot * 8) =
        *(const short8*)&lds[row * 64 + slot * 8];
  }
}

// ---------------- colmean (from fused sums) + recurrent state update ----------------
__global__ __launch_bounds__(1024) void colmean2_state_kernel(
    const float* __restrict__ csum, const float* __restrict__ state,
    const float* __restrict__ w_h2s, const float* __restrict__ w_sg,
    float* __restrict__ out_tail) {
  __shared__ float cms[2048];
  __shared__ float nis[128];
  int t = threadIdx.x;
#pragma unroll
  for (int i = 0; i < 2; ++i) {
    int idx = i * 1024 + t;              // 0..2047 = b*D + d
    cms[idx] = csum[idx] * (1.f / (float)S_);
  }
  __syncthreads();
  {
    int out = t >> 3, ks = t & 7;
    int b = out >> 6, j = out & 63;
    float ni = 0.f;
    int k0 = ks * 128;
#pragma unroll 8
    for (int k = k0; k < k0 + 128; ++k)
      ni += cms[b * 1024 + k] * w_h2s[k * SD_ + j];
    ni += __shfl_xor(ni, 1);
    ni += __shfl_xor(ni, 2);
    ni += __shfl_xor(ni, 4);
    if (ks == 0) nis[out] = ni;
  }
  __syncthreads();
  if (t < 128) {
    int b = t >> 6, j = t & 63;
    float nv = nis[t];
    float g = 0.f;
#pragma unroll
    for (int k = 0; k < SD_; ++k) g += state[b * SD_ + k] * w_sg[k * SD_ + j];
#pragma unroll
    for (int k = 0; k < SD_; ++k) g += nis[b * SD_ + k] * w_sg[(SD_ + k) * SD_ + j];
    g = 1.f / (1.f + __expf(-g));
    float st = state[b * SD_ + j];
    out_tail[t] = st * (1.f - g) + nv * g;
  }
}

extern "C" void kernel_launch(void* const* d_in, const int* in_sizes, int n_in,
                              void* d_out, int out_size, void* d_ws, size_t ws_size,
                              hipStream_t stream) {
  const float* x      = (const float*)d_in[0];
  const float* gamma  = (const float*)d_in[1];
  const float* beta   = (const float*)d_in[2];
  const float* state  = (const float*)d_in[3];
  const float* w_qkv  = (const float*)d_in[4];
  const float* w_o    = (const float*)d_in[5];
  const float* w_gate = (const float*)d_in[6];
  const float* w_up   = (const float*)d_in[7];
  const float* w_down = (const float*)d_in[8];
  const float* norm1w = (const float*)d_in[9];
  const float* norm2w = (const float*)d_in[10];
  const float* w_sm   = (const float*)d_in[11];
  const float* w_h2s  = (const float*)d_in[12];
  const float* w_sg   = (const float*)d_in[13];
  float* out = (float*)d_out;

  float* ws = (float*)d_ws;
  // ws layout (float units). h_bf/wT/wT2 are DEAD during attention (partials
  // overlay them); w_oT has a DEDICATED slot because it must survive attention.
  float*  fg     = ws;                          // 2048
  float*  fb     = ws + 2048;                   // 2048
  float*  csum   = ws + 8192;                   // 2048 (fused column sums)
  ushort* h_bf   = (ushort*)(ws + 65536);                    // 2097152 fl (8MB)
  ushort* wT     = (ushort*)(ws + 65536 + 2097152);          // 1572864 fl (6MB)
  ushort* wT2    = (ushort*)(ws + 65536 + 3670016);          // 1572864 fl (6MB)
  unsigned* PO   = (unsigned*)(ws + 65536);                  // 16*NT2 uints (16MB)
  float*  PM     = ws + 65536 + 4194304;                     // NT2 fl (1MB)
  float*  PL     = ws + 65536 + 4456448;                     // NT2 fl (1MB)
  ushort* AO_bf  = (ushort*)(ws + 65536 + 5242880);          // 2097152 fl (8MB)
  ushort* qkv_bf = (ushort*)(ws + 65536 + 7340032);          // 6291456 fl (24MB)
  ushort* Vt_g   = (ushort*)(ws + 65536 + 13631488);         // 2097152 fl (8MB)
  ushort* w_oT   = (ushort*)(ws + 65536 + 15728640);         // 524288 fl (2MB) — survives attn
  ushort* gu_bf  = qkv_bf;   // reuses qkv slot (dead after attention)

  // 0. zero the fused column-sum buffer (capture-safe)
  hipMemsetAsync(csum, 0, 2048 * sizeof(float), stream);
  // 1. FiLM params
  film_kernel<<<dim3(8, B_), 256, 0, stream>>>(state, w_sm, gamma, beta, fg, fb);
  // 2. h = rmsnorm(x,norm1)*fg + fb  -> bf16
  rmsnorm_film_kernel<<<M_, 256, 0, stream>>>(x, norm1w, fg, fb, h_bf);
  // 3. batched transpose (w_qkv -> wT, w_o -> w_oT) + qkv GEMM
  transpose_bf16_dual2<<<dim3(D3_ / 32, D_ / 32, 2), 256, 0, stream>>>(
      w_qkv, wT, D_, D3_, w_o, w_oT, D_, D_);
  gemm_mfma<4><<<(D3_ / 128) * (M_ / 128), 256, 0, stream>>>(
      h_bf, wT, nullptr, nullptr, qkv_bf, Vt_g, nullptr, M_, D3_, D_);
  // 4. attention: k-parity split main (512 blocks) + merge (256 blocks)
  attn_mfma_kernel<<<512, 512, 0, stream>>>(qkv_bf, Vt_g, PO, PM, PL);
  attn_merge_kernel<<<256, 512, 0, stream>>>(PO, PM, PL, AO_bf);
  // 5. x1 = x + AO @ w_o -> d_out (w_o^T in dedicated w_oT)
  gemm_mfma<3><<<(D_ / 128) * (M_ / 128), 256, 0, stream>>>(
      AO_bf, w_oT, x, out, nullptr, nullptr, nullptr, M_, D_, D_);
  // 6. h2 = rmsnorm(x1,norm2)*fg + fb -> bf16
  rmsnorm_film_kernel<<<M_, 256, 0, stream>>>(out, norm2w, fg, fb, h_bf);
  // 7+8. gu = silu(h2 @ w_gate) * (h2 @ w_up)  (fused dual GEMM)
  transpose_bf16_dual2<<<dim3(D3_ / 32, D_ / 32, 2), 256, 0, stream>>>(
      w_gate, wT, D_, D3_, w_up, wT2, D_, D3_);
  gemm_dual<<<(D3_ / 128) * (M_ / 128), 256, 0, stream>>>(
      h_bf, wT, wT2, gu_bf, M_, D3_, D_);
  // 9. x2 = x1 + gu @ w_down -> d_out, with fused column-sum (EPI=5)
  transpose_bf16<<<dim3(D_ / 32, D3_ / 32), 256, 0, stream>>>(w_down, wT, D3_, D_);
  gemm_mfma<5><<<(D_ / 128) * (M_ / 128), 256, 0, stream>>>(
      gu_bf, wT, out, out, nullptr, nullptr, csum, M_, D_, D3_);
  // 10. state update from fused sums
  colmean2_state_kernel<<<1, 1024, 0, stream>>>(csum, state, w_h2s, w_sg,
                                                out + (size_t)M_ * D_);
}

// Round 16
// 295.789 us; speedup vs baseline: 1.0741x; 1.0741x over previous
//
#include <hip/hip_runtime.h>
#include <hip/hip_bf16.h>

#define EPS_RMS 1.1920929e-07f

constexpr int B_ = 2, S_ = 2048, D_ = 1024, H_ = 16, HD_ = 64, SD_ = 64;
constexpr int M_ = B_ * S_;      // 4096 rows
constexpr int D3_ = 3 * D_;      // 3072
constexpr int NT2_ = 512 * 512;  // partial-buffer stride (blocks x threads)

using short8 = __attribute__((ext_vector_type(8))) short;
using f32x4  = __attribute__((ext_vector_type(4))) float;
using f32x16 = __attribute__((ext_vector_type(16))) float;
typedef int v2i __attribute__((ext_vector_type(2)));

static __device__ __forceinline__ ushort f2bf(float x) {
  __hip_bfloat16 h = __float2bfloat16(x);
  return *reinterpret_cast<ushort*>(&h);
}
static __device__ __forceinline__ float bf2f(ushort u) {
  __hip_bfloat16 h;
  *reinterpret_cast<ushort*>(&h) = u;
  return __bfloat162float(h);
}
static __device__ __forceinline__ unsigned pk2(float lo, float hi) {
  return (unsigned)f2bf(lo) | ((unsigned)f2bf(hi) << 16);
}
// v_permlane32_swap_b32: ret.x = [a.lo, b.lo], ret.y = [a.hi, b.hi]
static __device__ __forceinline__ v2i swap32(int a, int b) {
  return __builtin_amdgcn_permlane32_swap(a, b, false, false);
}
struct alignas(8) bf4 { ushort a, b, c, d; };

// async global->LDS, 16B per lane; LDS dest = wave-uniform base + lane*16
static __device__ __forceinline__ void gload16(const ushort* g, ushort* l) {
  __builtin_amdgcn_global_load_lds(
      (const __attribute__((address_space(1))) unsigned int*)g,
      (__attribute__((address_space(3))) unsigned int*)l, 16, 0, 0);
}

// ---------------- FiLM modulation ----------------
__global__ void film_kernel(const float* __restrict__ state,
                            const float* __restrict__ w_sm,
                            const float* __restrict__ gamma,
                            const float* __restrict__ beta,
                            float* __restrict__ fg, float* __restrict__ fb) {
  int c = blockIdx.x * 256 + threadIdx.x;   // 0..2047
  int b = blockIdx.y;
  float acc = 0.f;
#pragma unroll 8
  for (int k = 0; k < SD_; ++k)
    acc += state[b * SD_ + k] * w_sm[k * (2 * D_) + c];
  if (c < D_) fg[b * D_ + c] = gamma[c] * (1.f + acc);
  else        fb[b * D_ + (c - D_)] = beta[c - D_] + acc;
}

// ---------------- RMSNorm + FiLM -> bf16 ----------------
__global__ __launch_bounds__(256) void rmsnorm_film_kernel(
    const float* __restrict__ X, const float* __restrict__ nw,
    const float* __restrict__ fg, const float* __restrict__ fb,
    ushort* __restrict__ Hout) {
  int row = blockIdx.x;            // 0..4095
  int b = row / S_;
  int t = threadIdx.x;
  const float4* x4 = (const float4*)(X + (size_t)row * D_);
  float4 xv = x4[t];
  float ss = xv.x * xv.x + xv.y * xv.y + xv.z * xv.z + xv.w * xv.w;
#pragma unroll
  for (int off = 32; off >= 1; off >>= 1) ss += __shfl_xor(ss, off);
  __shared__ float red[4];
  if ((t & 63) == 0) red[t >> 6] = ss;
  __syncthreads();
  float tot = red[0] + red[1] + red[2] + red[3];
  float scale = rsqrtf(tot / (float)D_ + EPS_RMS);
  int d = t * 4;
  const float4 nw4 = *(const float4*)(nw + d);
  const float4 g4  = *(const float4*)(fg + b * D_ + d);
  const float4 b4  = *(const float4*)(fb + b * D_ + d);
  bf4 hv;
  hv.a = f2bf(xv.x * scale * nw4.x * g4.x + b4.x);
  hv.b = f2bf(xv.y * scale * nw4.y * g4.y + b4.y);
  hv.c = f2bf(xv.z * scale * nw4.z * g4.z + b4.z);
  hv.d = f2bf(xv.w * scale * nw4.w * g4.w + b4.w);
  *(bf4*)(Hout + (size_t)row * D_ + d) = hv;
}

// ---------------- weight transpose + f32->bf16: Wt[n][k] = bf16(W[k][n]) ----------------
__global__ __launch_bounds__(256) void transpose_bf16(
    const float* __restrict__ W, ushort* __restrict__ Wt, int K, int N) {
  __shared__ float tile[32][33];
  int n0 = blockIdx.x * 32, k0 = blockIdx.y * 32;
  int t = threadIdx.x;
  int c = t & 31, r = t >> 5;
#pragma unroll
  for (int p = 0; p < 4; ++p)
    tile[r + 8 * p][c] = W[(size_t)(k0 + r + 8 * p) * N + n0 + c];
  __syncthreads();
#pragma unroll
  for (int p = 0; p < 4; ++p)
    Wt[(size_t)(n0 + r + 8 * p) * K + k0 + c] = f2bf(tile[c][r + 8 * p]);
}

// dual variant: z=0 transposes (W0->T0), z=1 (W1->T1)
__global__ __launch_bounds__(256) void transpose_bf16_dual(
    const float* __restrict__ W0, ushort* __restrict__ T0,
    const float* __restrict__ W1, ushort* __restrict__ T1, int K, int N) {
  const float* W = blockIdx.z ? W1 : W0;
  ushort* Wt = blockIdx.z ? T1 : T0;
  __shared__ float tile[32][33];
  int n0 = blockIdx.x * 32, k0 = blockIdx.y * 32;
  int t = threadIdx.x;
  int c = t & 31, r = t >> 5;
#pragma unroll
  for (int p = 0; p < 4; ++p)
    tile[r + 8 * p][c] = W[(size_t)(k0 + r + 8 * p) * N + n0 + c];
  __syncthreads();
#pragma unroll
  for (int p = 0; p < 4; ++p)
    Wt[(size_t)(n0 + r + 8 * p) * K + k0 + c] = f2bf(tile[c][r + 8 * p]);
}

// ---------------- MFMA micro-tile compute: one BK=64 K-tile ----------------
static __device__ __forceinline__ void mfma_tile(
    const char* Au, const char* Bu, f32x4 (&acc)[4][4],
    int l15, int l4, int swz, int wr, int wc) {
#pragma unroll
  for (int kk = 0; kk < 2; ++kk) {
    int tslot = ((kk * 4 + l4) ^ swz) << 4;
    short8 a[4], b[4];
#pragma unroll
    for (int i = 0; i < 4; ++i) {
      int arow = wr * 64 + i * 16 + l15;
      int brow = wc * 64 + i * 16 + l15;
      a[i] = *(const short8*)(Au + arow * 128 + tslot);
      b[i] = *(const short8*)(Bu + brow * 128 + tslot);
    }
#pragma unroll
    for (int m = 0; m < 4; ++m)
#pragma unroll
      for (int n = 0; n < 4; ++n)
        acc[m][n] = __builtin_amdgcn_mfma_f32_16x16x32_bf16(a[m], b[n], acc[m][n], 0, 0, 0);
  }
}

// block swizzle helper: XCD-chunked 2D (GROUP_M=8, bn-fast)
static __device__ __forceinline__ void block_swizzle(int bid, int M, int N,
                                                     int& bm, int& bn) {
  int nbn = N >> 7;
  int nb  = nbn * (M >> 7);
  int qx  = nb >> 3;
  int lin = (bid & 7) * qx + (bid >> 3);
  int grp = lin / (nbn << 3), rem = lin % (nbn << 3);
  bm = ((grp << 3) + (rem & 7)) << 7;
  bn = (rem >> 3) << 7;
}

// ---------------- bf16 MFMA GEMM: C = A(MxK) @ Bt(NxK)^T ----------------
// EPI: 3 = Res+acc->f32; 4 = qkv split: cols<2048 -> bf16 Cb; cols>=2048 -> V^T
// (256,4): VGPR 64-84 <= 128 cap, LDS 32KB x4 <= 160 -> 4 blocks/CU
template<int EPI>
__global__ __launch_bounds__(256, 4) void gemm_mfma(
    const ushort* __restrict__ A, const ushort* __restrict__ Bt,
    const float* __restrict__ Res,
    float* __restrict__ Cf, ushort* __restrict__ Cb, ushort* __restrict__ VtP,
    int M, int N, int K) {
  __shared__ ushort smem[16384];       // 32KB: A [0,8192) ushorts, B [8192,16384)
  char* Au = (char*)smem;
  char* Bu = (char*)(smem + 8192);
  int t = threadIdx.x;
  int bm, bn;
  block_swizzle(blockIdx.x, M, N, bm, bn);

  int lane = t & 63, wid = t >> 6;
  int wr = wid >> 1, wc = wid & 1;
  int l15 = lane & 15, l4 = lane >> 4;
  int swz = l15 & 7;

  const ushort* gA[4];
  const ushort* gB[4];
  ushort* lA[4];
  ushort* lB[4];
#pragma unroll
  for (int p = 0; p < 4; ++p) {
    int seg = p * 4 + wid;
    int flat = seg * 64 + lane;
    int row = flat >> 3, sl = flat & 7;
    int gc = ((sl ^ (row & 7)) << 3);    // inverse-swizzled source column
    gA[p] = A  + (size_t)(bm + row) * K + gc;
    gB[p] = Bt + (size_t)(bn + row) * K + gc;
    lA[p] = smem + seg * 512;            // wave-uniform base
    lB[p] = smem + 8192 + seg * 512;
  }

  f32x4 acc[4][4];
#pragma unroll
  for (int m = 0; m < 4; ++m)
#pragma unroll
    for (int n = 0; n < 4; ++n) acc[m][n] = (f32x4){0.f, 0.f, 0.f, 0.f};

  int nk = K >> 6;
  for (int kt = 0; kt < nk; ++kt) {
    __syncthreads();
#pragma unroll
    for (int p = 0; p < 4; ++p) {
      gload16(gA[p], lA[p]);
      gload16(gB[p], lB[p]);
      gA[p] += 64; gB[p] += 64;
    }
    __syncthreads();
    mfma_tile(Au, Bu, acc, l15, l4, swz, wr, wc);
  }

  if constexpr (EPI == 3) {
#pragma unroll
    for (int m = 0; m < 4; ++m)
#pragma unroll
      for (int n = 0; n < 4; ++n) {
        int row0 = bm + wr * 64 + m * 16 + l4 * 4;
        int col  = bn + wc * 64 + n * 16 + l15;
#pragma unroll
        for (int j = 0; j < 4; ++j) {
          size_t idx = (size_t)(row0 + j) * (size_t)N + col;
          Cf[idx] = Res[idx] + acc[m][n][j];
        }
      }
  } else {
    // LDS-staged coalesced bf16 epilogue
    __syncthreads();
    ushort* Es = smem;                   // 128x128 bf16 = 32KB
    bool vblk = (bn >= 2048);
#pragma unroll
    for (int m = 0; m < 4; ++m)
#pragma unroll
      for (int n = 0; n < 4; ++n) {
        int rb0 = wr * 64 + m * 16 + l4 * 4;
        int c   = wc * 64 + n * 16 + l15;
#pragma unroll
        for (int j = 0; j < 4; ++j) {
          float v = acc[m][n][j];
          int r = rb0 + j;
          if (vblk) Es[c * 128 + (r ^ ((c & 15) << 3))] = f2bf(v);  // transposed + XOR perm
          else      Es[r * 128 + c] = f2bf(v);
        }
      }
    __syncthreads();
    if (vblk) {
#pragma unroll
      for (int p = 0; p < 8; ++p) {
        int flat = p * 256 + t;
        int c = flat >> 4, r8 = (flat & 15) * 8;
        int vc = bn - 2048 + c, hh = vc >> 6, dd = vc & 63;
        int bbv = bm >> 11, s0 = (bm & 2047) + r8;
        *(short8*)(VtP + ((((size_t)bbv * 16 + hh) * 64 + dd) << 11) + s0) =
            *(const short8*)&Es[c * 128 + (r8 ^ ((c & 15) << 3))];
      }
    } else {
#pragma unroll
      for (int p = 0; p < 8; ++p) {
        int flat = p * 256 + t;
        int r = flat >> 4, c8 = (flat & 15) * 8;
        *(short8*)(Cb + (size_t)(bm + r) * N + bn + c8) = *(const short8*)&Es[r * 128 + c8];
      }
    }
  }
}

// ---------------- fused dual GEMM: Cb = silu(A@Gt^T) * (A@Ut^T), bf16 ----------------
// NOTE: (256,2) required — ag+au accumulators alone are 128 VGPRs (R10 spill lesson).
__global__ __launch_bounds__(256, 2) void gemm_dual(
    const ushort* __restrict__ A, const ushort* __restrict__ Gt,
    const ushort* __restrict__ Ut, ushort* __restrict__ Cb,
    int M, int N, int K) {
  __shared__ ushort smem[24576];       // 48KB: A, Bg, Bu tiles
  char* Au = (char*)smem;
  char* Gu = (char*)(smem + 8192);
  char* Uu = (char*)(smem + 16384);
  int t = threadIdx.x;
  int bm, bn;
  block_swizzle(blockIdx.x, M, N, bm, bn);

  int lane = t & 63, wid = t >> 6;
  int wr = wid >> 1, wc = wid & 1;
  int l15 = lane & 15, l4 = lane >> 4;
  int swz = l15 & 7;

  const ushort* gA[4]; const ushort* gG[4]; const ushort* gU[4];
  ushort* lA[4]; ushort* lG[4]; ushort* lU[4];
#pragma unroll
  for (int p = 0; p < 4; ++p) {
    int seg = p * 4 + wid;
    int flat = seg * 64 + lane;
    int row = flat >> 3, sl = flat & 7;
    int gc = ((sl ^ (row & 7)) << 3);
    gA[p] = A  + (size_t)(bm + row) * K + gc;
    gG[p] = Gt + (size_t)(bn + row) * K + gc;
    gU[p] = Ut + (size_t)(bn + row) * K + gc;
    lA[p] = smem + seg * 512;
    lG[p] = smem + 8192 + seg * 512;
    lU[p] = smem + 16384 + seg * 512;
  }

  f32x4 ag[4][4], au[4][4];
#pragma unroll
  for (int m = 0; m < 4; ++m)
#pragma unroll
    for (int n = 0; n < 4; ++n) {
      ag[m][n] = (f32x4){0.f, 0.f, 0.f, 0.f};
      au[m][n] = (f32x4){0.f, 0.f, 0.f, 0.f};
    }

  int nk = K >> 6;
  for (int kt = 0; kt < nk; ++kt) {
    __syncthreads();
#pragma unroll
    for (int p = 0; p < 4; ++p) {
      gload16(gA[p], lA[p]);
      gload16(gG[p], lG[p]);
      gload16(gU[p], lU[p]);
      gA[p] += 64; gG[p] += 64; gU[p] += 64;
    }
    __syncthreads();
#pragma unroll
    for (int kk = 0; kk < 2; ++kk) {
      int tslot = ((kk * 4 + l4) ^ swz) << 4;
      short8 a[4], bg[4], bu[4];
#pragma unroll
      for (int i = 0; i < 4; ++i) {
        int arow = wr * 64 + i * 16 + l15;
        int brow = wc * 64 + i * 16 + l15;
        a[i]  = *(const short8*)(Au + arow * 128 + tslot);
        bg[i] = *(const short8*)(Gu + brow * 128 + tslot);
        bu[i] = *(const short8*)(Uu + brow * 128 + tslot);
      }
#pragma unroll
      for (int m = 0; m < 4; ++m)
#pragma unroll
        for (int n = 0; n < 4; ++n) {
          ag[m][n] = __builtin_amdgcn_mfma_f32_16x16x32_bf16(a[m], bg[n], ag[m][n], 0, 0, 0);
          au[m][n] = __builtin_amdgcn_mfma_f32_16x16x32_bf16(a[m], bu[n], au[m][n], 0, 0, 0);
        }
    }
  }

  __syncthreads();
  ushort* Es = smem;
#pragma unroll
  for (int m = 0; m < 4; ++m)
#pragma unroll
    for (int n = 0; n < 4; ++n) {
      int rb0 = wr * 64 + m * 16 + l4 * 4;
      int c   = wc * 64 + n * 16 + l15;
#pragma unroll
      for (int j = 0; j < 4; ++j) {
        float gv = ag[m][n][j];
        float v = gv / (1.f + __expf(-gv)) * au[m][n][j];
        Es[(rb0 + j) * 128 + c] = f2bf(v);
      }
    }
  __syncthreads();
#pragma unroll
  for (int p = 0; p < 8; ++p) {
    int flat = p * 256 + t;
    int r = flat >> 4, c8 = (flat & 15) * 8;
    *(short8*)(Cb + (size_t)(bm + r) * N + bn + c8) = *(const short8*)&Es[r * 128 + c8];
  }
}

// ---------------- MFMA causal flash attention, k-parity split ----------------
// 512 blocks x 8 waves, (512,4) -> 2 co-resident blocks/CU = 4 waves/SIMD with
// de-correlated barriers. Partial (m, l, O-bf16) dumped to workspace; merged
// by attn_merge_kernel. kh=0 always covers tile 0 -> l0 > 0.
__global__ __launch_bounds__(512, 4) void attn_mfma_kernel(
    const ushort* __restrict__ qkv,   // [B*S][3072] bf16 (Q at 0, K at 1024)
    const ushort* __restrict__ Vt,    // [B*H][64][2048] bf16
    unsigned* __restrict__ PO,        // [16][NT2] packed bf16x2 O-partials
    float* __restrict__ PM, float* __restrict__ PL) {  // [NT2] each
  __shared__ ushort lds[16384];       // 2 x (K 4096 + V 4096)
  const float SL2 = 0.125f * 1.44269504f;   // scale * log2(e)
  int t = threadIdx.x;
  int x = blockIdx.x;
  int lin = ((x & 7) << 6) + (x >> 3);   // XCD chunks of 64 blocks
  int kh = lin & 1;
  int pp = (lin >> 1) & 7;
  int hb = lin >> 4;                     // 0..31
  int h = hb & 15, bb = hb >> 4;
  int lane = t & 63, wv = t >> 6;        // wv 0..7
  int qi = wv >> 2, wsub = wv & 3;
  int qt = qi ? (15 - pp) : pp;
  int q0 = qt * 128;
  int l31 = lane & 31, g = lane >> 5;

  int qrow = q0 + wsub * 32 + l31;
  const ushort* qrow_ptr = qkv + (size_t)(bb * S_ + qrow) * 3072 + h * 64;
  short8 qf[4];
#pragma unroll
  for (int s = 0; s < 4; ++s) qf[s] = *(const short8*)(qrow_ptr + s * 16 + g * 8);

  f32x16 accO[2];
#pragma unroll
  for (int u = 0; u < 2; ++u)
#pragma unroll
    for (int r = 0; r < 16; ++r) accO[u][r] = 0.f;
  float m = -INFINITY, l = 0.f;
  int qg = qrow;
  int qmin = q0 + wsub * 32, qmax = qmin + 31;
  int ntpair = 2 * (16 - pp);            // full staged span of the pair
  int ntk = (ntpair - kh + 1) >> 1;      // this block's tile count (parity kh)

  const ushort* kbase = qkv + (size_t)(bb * S_) * 3072 + 1024 + h * 64;
  const ushort* vbase = Vt + ((size_t)(bb * 16 + h) * 64) * 2048;

  int srow = t >> 3, sslot = t & 7;
  int soff = srow * 64 + ((sslot ^ (srow & 7)) << 3);
  const ushort* kg0 = kbase + (size_t)srow * 3072 + sslot * 8;
  const ushort* vg0 = vbase + (size_t)srow * 2048 + sslot * 8;

  // prologue: stage tile kh into buf 0
  *(short8*)&lds[soff] = *(const short8*)(kg0 + (size_t)kh * (64 * 3072));
  *(short8*)&lds[4096 + soff] = *(const short8*)(vg0 + kh * 64);
  __syncthreads();

  for (int i2 = 0; i2 < ntk; ++i2) {
    int cur = i2 & 1;
    int kti = 2 * i2 + kh;
    int kt = kti << 6;
    bool pf = (i2 + 1 < ntk);
    short8 rk, rv;
    if (pf) {                            // issue next-parity-tile loads early
      rk = *(const short8*)(kg0 + (size_t)(kti + 2) * (64 * 3072));
      rv = *(const short8*)(vg0 + (kti + 2) * 64);
    }
    if (kt <= qmax) {
      const ushort* Kb = lds + cur * 8192;
      const ushort* Vb = Kb + 4096;

      f32x16 accT[2];
#pragma unroll
      for (int t2 = 0; t2 < 2; ++t2)
#pragma unroll
        for (int r = 0; r < 16; ++r) accT[t2][r] = 0.f;
      __builtin_amdgcn_s_setprio(1);
#pragma unroll
      for (int t2 = 0; t2 < 2; ++t2) {
        int key = 32 * t2 + l31;
#pragma unroll
        for (int s = 0; s < 4; ++s) {
          short8 kf = *(const short8*)&Kb[key * 64 + (((2 * s + g) ^ (key & 7)) << 3)];
          accT[t2] = __builtin_amdgcn_mfma_f32_32x32x16_bf16(kf, qf[s], accT[t2], 0, 0, 0);
        }
      }
      __builtin_amdgcn_s_setprio(0);

      bool need_mask = (kt + 63 > qmin);
      float p_[2][16];
      float pmax = -INFINITY;
#pragma unroll
      for (int t2 = 0; t2 < 2; ++t2)
#pragma unroll
        for (int r = 0; r < 16; ++r) {
          float v = accT[t2][r] * SL2;
          if (need_mask) {
            int key = kt + 32 * t2 + (r & 3) + 8 * (r >> 2) + 4 * g;
            if (key > qg) v = -INFINITY;
          }
          p_[t2][r] = v;
          pmax = fmaxf(pmax, v);
        }
      {
        v2i pm = swap32(__float_as_int(pmax), __float_as_int(pmax));
        pmax = fmaxf(pmax, __int_as_float(g ? pm.x : pm.y));
      }

      if (__any(pmax > m + 11.5f)) {     // defer-max
        float mnew = fmaxf(m, pmax);
        float corr = exp2f(m - mnew);
        m = mnew;
        l *= corr;
        float cr[16];
#pragma unroll
        for (int r = 0; r < 16; ++r) cr[r] = __shfl(corr, (r & 3) + 8 * (r >> 2) + 4 * g);
#pragma unroll
        for (int r = 0; r < 16; ++r) { accO[0][r] *= cr[r]; accO[1][r] *= cr[r]; }
      }
      float psum = 0.f;
#pragma unroll
      for (int t2 = 0; t2 < 2; ++t2)
#pragma unroll
        for (int r = 0; r < 16; ++r) {
          float e = exp2f(p_[t2][r] - m);
          p_[t2][r] = e;
          psum += e;
        }
      {
        v2i ps = swap32(__float_as_int(psum), __float_as_int(psum));
        psum += __int_as_float(g ? ps.x : ps.y);
      }
      l += psum;

#pragma unroll
      for (int s = 0; s < 4; ++s) {
        int ca = 2 * s, cb2 = 2 * s + 1;
        int ta = ca >> 2, ra = (ca & 3) * 4;
        int tb = cb2 >> 2, rbq = (cb2 & 3) * 4;
        int w0a = (int)pk2(p_[ta][ra], p_[ta][ra + 1]);
        int w1a = (int)pk2(p_[ta][ra + 2], p_[ta][ra + 3]);
        int w0b = (int)pk2(p_[tb][rbq], p_[tb][rbq + 1]);
        int w1b = (int)pk2(p_[tb][rbq + 2], p_[tb][rbq + 3]);
        v2i r0 = swap32(w0a, w0b);
        v2i r1 = swap32(w1a, w1b);
        union { int u[4]; short8 s8; } pa;
        pa.u[0] = r0.x;
        pa.u[1] = r1.x;
        pa.u[2] = r0.y;
        pa.u[3] = r1.y;
        __builtin_amdgcn_s_setprio(1);
#pragma unroll
        for (int u = 0; u < 2; ++u) {
          int d = 32 * u + l31;
          short8 vf = *(const short8*)&Vb[d * 64 + (((2 * s + g) ^ (d & 7)) << 3)];
          accO[u] = __builtin_amdgcn_mfma_f32_32x32x16_bf16(pa.s8, vf, accO[u], 0, 0, 0);
        }
        __builtin_amdgcn_s_setprio(0);
      }
    }
    if (pf) {                            // write prefetched tile into other buffer
      ushort* dst = lds + (cur ^ 1) * 8192;
      *(short8*)&dst[soff] = rk;
      *(short8*)&dst[4096 + soff] = rv;
    }
    __syncthreads();
  }

  // dump partials (coalesced SoA; O as packed bf16 pairs)
  size_t base = (size_t)lin * 512 + t;
#pragma unroll
  for (int r = 0; r < 16; ++r)
    PO[(size_t)r * NT2_ + base] = pk2(accO[0][r], accO[1][r]);
  PM[base] = m;
  PL[base] = l;
}

// ---------------- attention partial merge (kh=0 + kh=1) ----------------
__global__ __launch_bounds__(512, 2) void attn_merge_kernel(
    const unsigned* __restrict__ PO, const float* __restrict__ PM,
    const float* __restrict__ PL, ushort* __restrict__ AO) {
  __shared__ ushort lds[16384];
  int t = threadIdx.x;
  int xb = blockIdx.x;
  int lin2 = ((xb & 7) << 5) + (xb >> 3);   // XCD chunks of 32
  int pp = lin2 & 7;
  int hb = lin2 >> 3;
  int h = hb & 15, bb = hb >> 4;
  int lane = t & 63, wv = t >> 6;
  int l31 = lane & 31, g = lane >> 5;

  size_t p0 = ((size_t)((hb << 4) | (pp << 1)) * 512) + t;
  size_t p1 = p0 + 512;
  float m0 = PM[p0], l0 = PL[p0];
  float m1 = PM[p1], l1 = PL[p1];
  float mn = fmaxf(m0, m1);
  float c0 = exp2f(m0 - mn), c1 = exp2f(m1 - mn);   // m1=-inf -> c1=0
  float linv = 1.f / (l0 * c0 + l1 * c1);

  float cr0[16], cr1[16], lr[16];
#pragma unroll
  for (int r = 0; r < 16; ++r) {
    int src = (r & 3) + 8 * (r >> 2) + 4 * g;
    cr0[r] = __shfl(c0, src);
    cr1[r] = __shfl(c1, src);
    lr[r]  = __shfl(linv, src);
  }
#pragma unroll
  for (int r = 0; r < 16; ++r) {
    unsigned u0 = PO[(size_t)r * NT2_ + p0];
    unsigned u1 = PO[(size_t)r * NT2_ + p1];
    float a0 = bf2f((ushort)(u0 & 0xffff)), b0 = bf2f((ushort)(u0 >> 16));
    float a1 = bf2f((ushort)(u1 & 0xffff)), b1 = bf2f((ushort)(u1 >> 16));
    int row = wv * 32 + (r & 3) + 8 * (r >> 2) + 4 * g;
    lds[row * 64 + l31]      = f2bf((a0 * cr0[r] + a1 * cr1[r]) * lr[r]);
    lds[row * 64 + 32 + l31] = f2bf((b0 * cr0[r] + b1 * cr1[r]) * lr[r]);
  }
  __syncthreads();
#pragma unroll
  for (int p = 0; p < 4; ++p) {
    int flat = p * 512 + t;              // 0..2047
    int row = flat >> 3, slot = flat & 7;
    int qto = (row < 128) ? pp : (15 - pp);
    int grow = row & 127;
    *(short8*)(AO + (size_t)(bb * S_ + qto * 128 + grow) * 1024 + h * 64 + slot * 8) =
        *(const short8*)&lds[row * 64 + slot * 8];
  }
}

// ---------------- column mean over S (stage 1) ----------------
__global__ void colmean1(const float* __restrict__ X, float* __restrict__ part) {
  int d = blockIdx.x * 256 + threadIdx.x;
  int b = blockIdx.y;
  int ch = blockIdx.z;
  float s = 0.f;
  int s0 = ch * (S_ / 16);
  for (int i = 0; i < S_ / 16; ++i)
    s += X[(size_t)(b * S_ + s0 + i) * D_ + d];
  part[(b * 16 + ch) * D_ + d] = s;
}

// ---------------- colmean stage 2 + recurrent state update (fused, 1 block) ----------------
__global__ __launch_bounds__(1024) void colmean2_state_kernel(
    const float* __restrict__ part, const float* __restrict__ state,
    const float* __restrict__ w_h2s, const float* __restrict__ w_sg,
    float* __restrict__ out_tail) {
  __shared__ float cms[2048];
  __shared__ float nis[128];
  int t = threadIdx.x;
#pragma unroll
  for (int i = 0; i < 2; ++i) {
    int idx = i * 1024 + t;              // 0..2047 = b*D + d
    int b = idx >> 10, d = idx & 1023;
    float s = 0.f;
#pragma unroll
    for (int c = 0; c < 16; ++c) s += part[(b * 16 + c) * D_ + d];
    cms[idx] = s * (1.f / (float)S_);
  }
  __syncthreads();
  {
    int out = t >> 3, ks = t & 7;
    int b = out >> 6, j = out & 63;
    float ni = 0.f;
    int k0 = ks * 128;
#pragma unroll 8
    for (int k = k0; k < k0 + 128; ++k)
      ni += cms[b * 1024 + k] * w_h2s[k * SD_ + j];
    ni += __shfl_xor(ni, 1);
    ni += __shfl_xor(ni, 2);
    ni += __shfl_xor(ni, 4);
    if (ks == 0) nis[out] = ni;
  }
  __syncthreads();
  if (t < 128) {
    int b = t >> 6, j = t & 63;
    float nv = nis[t];
    float g = 0.f;
#pragma unroll
    for (int k = 0; k < SD_; ++k) g += state[b * SD_ + k] * w_sg[k * SD_ + j];
#pragma unroll
    for (int k = 0; k < SD_; ++k) g += nis[b * SD_ + k] * w_sg[(SD_ + k) * SD_ + j];
    g = 1.f / (1.f + __expf(-g));
    float st = state[b * SD_ + j];
    out_tail[t] = st * (1.f - g) + nv * g;
  }
}

extern "C" void kernel_launch(void* const* d_in, const int* in_sizes, int n_in,
                              void* d_out, int out_size, void* d_ws, size_t ws_size,
                              hipStream_t stream) {
  const float* x      = (const float*)d_in[0];
  const float* gamma  = (const float*)d_in[1];
  const float* beta   = (const float*)d_in[2];
  const float* state  = (const float*)d_in[3];
  const float* w_qkv  = (const float*)d_in[4];
  const float* w_o    = (const float*)d_in[5];
  const float* w_gate = (const float*)d_in[6];
  const float* w_up   = (const float*)d_in[7];
  const float* w_down = (const float*)d_in[8];
  const float* norm1w = (const float*)d_in[9];
  const float* norm2w = (const float*)d_in[10];
  const float* w_sm   = (const float*)d_in[11];
  const float* w_h2s  = (const float*)d_in[12];
  const float* w_sg   = (const float*)d_in[13];
  float* out = (float*)d_out;

  float* ws = (float*)d_ws;
  // ws layout (float units). h_bf/wT/wT2 are DEAD during attention -> the
  // 20MB span doubles as the attention partial buffer (18.87MB needed).
  float*  fg     = ws;                          // 2048
  float*  fb     = ws + 2048;                   // 2048
  float*  part   = ws + 8192;                   // 32768
  ushort* h_bf   = (ushort*)(ws + 65536);                    // 2097152 fl (8MB)
  ushort* wT     = (ushort*)(ws + 65536 + 2097152);          // 1572864 fl (6MB)
  ushort* wT2    = (ushort*)(ws + 65536 + 3670016);          // 1572864 fl (6MB)
  unsigned* PO   = (unsigned*)(ws + 65536);                  // 16*NT2 uints (16MB)
  float*  PM     = ws + 65536 + 4194304;                     // NT2 fl (1MB)
  float*  PL     = ws + 65536 + 4456448;                     // NT2 fl (1MB)
  ushort* AO_bf  = (ushort*)(ws + 65536 + 5242880);          // 2097152 fl (8MB)
  ushort* qkv_bf = (ushort*)(ws + 65536 + 7340032);          // 6291456 fl (24MB)
  ushort* Vt_g   = (ushort*)(ws + 65536 + 13631488);         // 2097152 fl (8MB)
  ushort* gu_bf  = qkv_bf;   // reuses qkv slot (dead after attention)

  // 1. FiLM params
  film_kernel<<<dim3(8, B_), 256, 0, stream>>>(state, w_sm, gamma, beta, fg, fb);
  // 2. h = rmsnorm(x,norm1)*fg + fb  -> bf16
  rmsnorm_film_kernel<<<M_, 256, 0, stream>>>(x, norm1w, fg, fb, h_bf);
  // 3. qkv = h @ w_qkv  -> Q/K bf16 + V transposed
  transpose_bf16<<<dim3(D3_ / 32, D_ / 32), 256, 0, stream>>>(w_qkv, wT, D_, D3_);
  gemm_mfma<4><<<(D3_ / 128) * (M_ / 128), 256, 0, stream>>>(
      h_bf, wT, nullptr, nullptr, qkv_bf, Vt_g, M_, D3_, D_);
  // 4. attention: k-parity split main (512 blocks) + merge (256 blocks)
  attn_mfma_kernel<<<512, 512, 0, stream>>>(qkv_bf, Vt_g, PO, PM, PL);
  attn_merge_kernel<<<256, 512, 0, stream>>>(PO, PM, PL, AO_bf);
  // 5. x1 = x + AO @ w_o -> d_out
  transpose_bf16<<<dim3(D_ / 32, D_ / 32), 256, 0, stream>>>(w_o, wT, D_, D_);
  gemm_mfma<3><<<(D_ / 128) * (M_ / 128), 256, 0, stream>>>(
      AO_bf, wT, x, out, nullptr, nullptr, M_, D_, D_);
  // 6. h2 = rmsnorm(x1,norm2)*fg + fb -> bf16
  rmsnorm_film_kernel<<<M_, 256, 0, stream>>>(out, norm2w, fg, fb, h_bf);
  // 7+8. gu = silu(h2 @ w_gate) * (h2 @ w_up)  (fused dual GEMM)
  transpose_bf16_dual<<<dim3(D3_ / 32, D_ / 32, 2), 256, 0, stream>>>(
      w_gate, wT, w_up, wT2, D_, D3_);
  gemm_dual<<<(D3_ / 128) * (M_ / 128), 256, 0, stream>>>(
      h_bf, wT, wT2, gu_bf, M_, D3_, D_);
  // 9. x2 = x1 + gu @ w_down -> d_out
  transpose_bf16<<<dim3(D_ / 32, D3_ / 32), 256, 0, stream>>>(w_down, wT, D3_, D_);
  gemm_mfma<3><<<(D_ / 128) * (M_ / 128), 256, 0, stream>>>(
      gu_bf, wT, out, out, nullptr, nullptr, M_, D_, D3_);
  // 10. column mean + state update (parallel fused tail)
  colmean1<<<dim3(4, B_, 16), 256, 0, stream>>>(out, part);
  colmean2_state_kernel<<<1, 1024, 0, stream>>>(part, state, w_h2s, w_sg,
                                                out + (size_t)M_ * D_);
}

// Round 17
// 293.980 us; speedup vs baseline: 1.0808x; 1.0062x over previous
//
#include <hip/hip_runtime.h>
#include <hip/hip_bf16.h>

#define EPS_RMS 1.1920929e-07f

constexpr int B_ = 2, S_ = 2048, D_ = 1024, H_ = 16, HD_ = 64, SD_ = 64;
constexpr int M_ = B_ * S_;      // 4096 rows
constexpr int D3_ = 3 * D_;      // 3072
constexpr int NT2_ = 512 * 512;  // partial-buffer stride (blocks x threads)

using short8 = __attribute__((ext_vector_type(8))) short;
using f32x4  = __attribute__((ext_vector_type(4))) float;
using f32x16 = __attribute__((ext_vector_type(16))) float;
typedef int v2i __attribute__((ext_vector_type(2)));

static __device__ __forceinline__ ushort f2bf(float x) {
  __hip_bfloat16 h = __float2bfloat16(x);
  return *reinterpret_cast<ushort*>(&h);
}
static __device__ __forceinline__ float bf2f(ushort u) {
  __hip_bfloat16 h;
  *reinterpret_cast<ushort*>(&h) = u;
  return __bfloat162float(h);
}
static __device__ __forceinline__ unsigned pk2(float lo, float hi) {
  return (unsigned)f2bf(lo) | ((unsigned)f2bf(hi) << 16);
}
// v_permlane32_swap_b32: ret.x = [a.lo, b.lo], ret.y = [a.hi, b.hi]
static __device__ __forceinline__ v2i swap32(int a, int b) {
  return __builtin_amdgcn_permlane32_swap(a, b, false, false);
}
struct alignas(8) bf4 { ushort a, b, c, d; };

// async global->LDS, 16B per lane; LDS dest = wave-uniform base + lane*16
static __device__ __forceinline__ void gload16(const ushort* g, ushort* l) {
  __builtin_amdgcn_global_load_lds(
      (const __attribute__((address_space(1))) unsigned int*)g,
      (__attribute__((address_space(3))) unsigned int*)l, 16, 0, 0);
}

// ---------------- FiLM modulation ----------------
__global__ void film_kernel(const float* __restrict__ state,
                            const float* __restrict__ w_sm,
                            const float* __restrict__ gamma,
                            const float* __restrict__ beta,
                            float* __restrict__ fg, float* __restrict__ fb) {
  int c = blockIdx.x * 256 + threadIdx.x;   // 0..2047
  int b = blockIdx.y;
  float acc = 0.f;
#pragma unroll 8
  for (int k = 0; k < SD_; ++k)
    acc += state[b * SD_ + k] * w_sm[k * (2 * D_) + c];
  if (c < D_) fg[b * D_ + c] = gamma[c] * (1.f + acc);
  else        fb[b * D_ + (c - D_)] = beta[c - D_] + acc;
}

// ---------------- RMSNorm + FiLM -> bf16 ----------------
__global__ __launch_bounds__(256) void rmsnorm_film_kernel(
    const float* __restrict__ X, const float* __restrict__ nw,
    const float* __restrict__ fg, const float* __restrict__ fb,
    ushort* __restrict__ Hout) {
  int row = blockIdx.x;            // 0..4095
  int b = row / S_;
  int t = threadIdx.x;
  const float4* x4 = (const float4*)(X + (size_t)row * D_);
  float4 xv = x4[t];
  float ss = xv.x * xv.x + xv.y * xv.y + xv.z * xv.z + xv.w * xv.w;
#pragma unroll
  for (int off = 32; off >= 1; off >>= 1) ss += __shfl_xor(ss, off);
  __shared__ float red[4];
  if ((t & 63) == 0) red[t >> 6] = ss;
  __syncthreads();
  float tot = red[0] + red[1] + red[2] + red[3];
  float scale = rsqrtf(tot / (float)D_ + EPS_RMS);
  int d = t * 4;
  const float4 nw4 = *(const float4*)(nw + d);
  const float4 g4  = *(const float4*)(fg + b * D_ + d);
  const float4 b4  = *(const float4*)(fb + b * D_ + d);
  bf4 hv;
  hv.a = f2bf(xv.x * scale * nw4.x * g4.x + b4.x);
  hv.b = f2bf(xv.y * scale * nw4.y * g4.y + b4.y);
  hv.c = f2bf(xv.z * scale * nw4.z * g4.z + b4.z);
  hv.d = f2bf(xv.w * scale * nw4.w * g4.w + b4.w);
  *(bf4*)(Hout + (size_t)row * D_ + d) = hv;
}

// ---------------- weight transpose + f32->bf16: Wt[n][k] = bf16(W[k][n]) ----------------
__global__ __launch_bounds__(256) void transpose_bf16(
    const float* __restrict__ W, ushort* __restrict__ Wt, int K, int N) {
  __shared__ float tile[32][33];
  int n0 = blockIdx.x * 32, k0 = blockIdx.y * 32;
  int t = threadIdx.x;
  int c = t & 31, r = t >> 5;
#pragma unroll
  for (int p = 0; p < 4; ++p)
    tile[r + 8 * p][c] = W[(size_t)(k0 + r + 8 * p) * N + n0 + c];
  __syncthreads();
#pragma unroll
  for (int p = 0; p < 4; ++p)
    Wt[(size_t)(n0 + r + 8 * p) * K + k0 + c] = f2bf(tile[c][r + 8 * p]);
}

// dual variant: z=0 transposes (W0->T0), z=1 (W1->T1)
__global__ __launch_bounds__(256) void transpose_bf16_dual(
    const float* __restrict__ W0, ushort* __restrict__ T0,
    const float* __restrict__ W1, ushort* __restrict__ T1, int K, int N) {
  const float* W = blockIdx.z ? W1 : W0;
  ushort* Wt = blockIdx.z ? T1 : T0;
  __shared__ float tile[32][33];
  int n0 = blockIdx.x * 32, k0 = blockIdx.y * 32;
  int t = threadIdx.x;
  int c = t & 31, r = t >> 5;
#pragma unroll
  for (int p = 0; p < 4; ++p)
    tile[r + 8 * p][c] = W[(size_t)(k0 + r + 8 * p) * N + n0 + c];
  __syncthreads();
#pragma unroll
  for (int p = 0; p < 4; ++p)
    Wt[(size_t)(n0 + r + 8 * p) * K + k0 + c] = f2bf(tile[c][r + 8 * p]);
}

// ---------------- MFMA micro-tile compute: one BK=64 K-tile ----------------
static __device__ __forceinline__ void mfma_tile(
    const char* Au, const char* Bu, f32x4 (&acc)[4][4],
    int l15, int l4, int swz, int wr, int wc) {
#pragma unroll
  for (int kk = 0; kk < 2; ++kk) {
    int tslot = ((kk * 4 + l4) ^ swz) << 4;
    short8 a[4], b[4];
#pragma unroll
    for (int i = 0; i < 4; ++i) {
      int arow = wr * 64 + i * 16 + l15;
      int brow = wc * 64 + i * 16 + l15;
      a[i] = *(const short8*)(Au + arow * 128 + tslot);
      b[i] = *(const short8*)(Bu + brow * 128 + tslot);
    }
#pragma unroll
    for (int m = 0; m < 4; ++m)
#pragma unroll
      for (int n = 0; n < 4; ++n)
        acc[m][n] = __builtin_amdgcn_mfma_f32_16x16x32_bf16(a[m], b[n], acc[m][n], 0, 0, 0);
  }
}

// block swizzle helper: XCD-chunked 2D (GROUP_M=8, bn-fast)
static __device__ __forceinline__ void block_swizzle(int bid, int M, int N,
                                                     int& bm, int& bn) {
  int nbn = N >> 7;
  int nb  = nbn * (M >> 7);
  int qx  = nb >> 3;
  int lin = (bid & 7) * qx + (bid >> 3);
  int grp = lin / (nbn << 3), rem = lin % (nbn << 3);
  bm = ((grp << 3) + (rem & 7)) << 7;
  bn = (rem >> 3) << 7;
}

// ---------------- bf16 MFMA GEMM: C = A(MxK) @ Bt(NxK)^T ----------------
// EPI: 3 = Res+acc->f32; 4 = qkv split: cols<2048 -> bf16 Cb; cols>=2048 -> V^T
// (256,4): VGPR 64-84 <= 128 cap, LDS 32KB x4 <= 160 -> 4 blocks/CU
template<int EPI>
__global__ __launch_bounds__(256, 4) void gemm_mfma(
    const ushort* __restrict__ A, const ushort* __restrict__ Bt,
    const float* __restrict__ Res,
    float* __restrict__ Cf, ushort* __restrict__ Cb, ushort* __restrict__ VtP,
    int M, int N, int K) {
  __shared__ ushort smem[16384];       // 32KB: A [0,8192) ushorts, B [8192,16384)
  char* Au = (char*)smem;
  char* Bu = (char*)(smem + 8192);
  int t = threadIdx.x;
  int bm, bn;
  block_swizzle(blockIdx.x, M, N, bm, bn);

  int lane = t & 63, wid = t >> 6;
  int wr = wid >> 1, wc = wid & 1;
  int l15 = lane & 15, l4 = lane >> 4;
  int swz = l15 & 7;

  const ushort* gA[4];
  const ushort* gB[4];
  ushort* lA[4];
  ushort* lB[4];
#pragma unroll
  for (int p = 0; p < 4; ++p) {
    int seg = p * 4 + wid;
    int flat = seg * 64 + lane;
    int row = flat >> 3, sl = flat & 7;
    int gc = ((sl ^ (row & 7)) << 3);    // inverse-swizzled source column
    gA[p] = A  + (size_t)(bm + row) * K + gc;
    gB[p] = Bt + (size_t)(bn + row) * K + gc;
    lA[p] = smem + seg * 512;            // wave-uniform base
    lB[p] = smem + 8192 + seg * 512;
  }

  f32x4 acc[4][4];
#pragma unroll
  for (int m = 0; m < 4; ++m)
#pragma unroll
    for (int n = 0; n < 4; ++n) acc[m][n] = (f32x4){0.f, 0.f, 0.f, 0.f};

  int nk = K >> 6;
  for (int kt = 0; kt < nk; ++kt) {
    __syncthreads();
#pragma unroll
    for (int p = 0; p < 4; ++p) {
      gload16(gA[p], lA[p]);
      gload16(gB[p], lB[p]);
      gA[p] += 64; gB[p] += 64;
    }
    __syncthreads();
    mfma_tile(Au, Bu, acc, l15, l4, swz, wr, wc);
  }

  if constexpr (EPI == 3) {
#pragma unroll
    for (int m = 0; m < 4; ++m)
#pragma unroll
      for (int n = 0; n < 4; ++n) {
        int row0 = bm + wr * 64 + m * 16 + l4 * 4;
        int col  = bn + wc * 64 + n * 16 + l15;
#pragma unroll
        for (int j = 0; j < 4; ++j) {
          size_t idx = (size_t)(row0 + j) * (size_t)N + col;
          Cf[idx] = Res[idx] + acc[m][n][j];
        }
      }
  } else {
    // LDS-staged coalesced bf16 epilogue
    __syncthreads();
    ushort* Es = smem;                   // 128x128 bf16 = 32KB
    bool vblk = (bn >= 2048);
#pragma unroll
    for (int m = 0; m < 4; ++m)
#pragma unroll
      for (int n = 0; n < 4; ++n) {
        int rb0 = wr * 64 + m * 16 + l4 * 4;
        int c   = wc * 64 + n * 16 + l15;
#pragma unroll
        for (int j = 0; j < 4; ++j) {
          float v = acc[m][n][j];
          int r = rb0 + j;
          if (vblk) Es[c * 128 + (r ^ ((c & 15) << 3))] = f2bf(v);  // transposed + XOR perm
          else      Es[r * 128 + c] = f2bf(v);
        }
      }
    __syncthreads();
    if (vblk) {
#pragma unroll
      for (int p = 0; p < 8; ++p) {
        int flat = p * 256 + t;
        int c = flat >> 4, r8 = (flat & 15) * 8;
        int vc = bn - 2048 + c, hh = vc >> 6, dd = vc & 63;
        int bbv = bm >> 11, s0 = (bm & 2047) + r8;
        *(short8*)(VtP + ((((size_t)bbv * 16 + hh) * 64 + dd) << 11) + s0) =
            *(const short8*)&Es[c * 128 + (r8 ^ ((c & 15) << 3))];
      }
    } else {
#pragma unroll
      for (int p = 0; p < 8; ++p) {
        int flat = p * 256 + t;
        int r = flat >> 4, c8 = (flat & 15) * 8;
        *(short8*)(Cb + (size_t)(bm + r) * N + bn + c8) = *(const short8*)&Es[r * 128 + c8];
      }
    }
  }
}

// ---------------- fused dual GEMM: Cb = silu(A@Gt^T) * (A@Ut^T), bf16 ----------------
// 8-wave blocks (512 thr), 2x4 wave grid, 64x32 per-wave tile: acc halves to
// 64 VGPRs -> fits the (512,4) 128-VGPR cap -> 2 blocks/CU = 4 waves/SIMD
// (was 2) for barrier-drain hiding. LDS 48KB unchanged.
__global__ __launch_bounds__(512, 4) void gemm_dual(
    const ushort* __restrict__ A, const ushort* __restrict__ Gt,
    const ushort* __restrict__ Ut, ushort* __restrict__ Cb,
    int M, int N, int K) {
  __shared__ ushort smem[24576];       // 48KB: A, Bg, Bu tiles
  char* Au = (char*)smem;
  char* Gu = (char*)(smem + 8192);
  char* Uu = (char*)(smem + 16384);
  int t = threadIdx.x;
  int bm, bn;
  block_swizzle(blockIdx.x, M, N, bm, bn);

  int lane = t & 63, wid = t >> 6;      // wid 0..7
  int wr = wid >> 2, wc = wid & 3;      // 2x4 wave grid; wave tile 64 x 32
  int l15 = lane & 15, l4 = lane >> 4;
  int swz = l15 & 7;

  // staging: 2 passes x 8 waves cover one 128x64 bf16 tile per array
  const ushort* gA[2]; const ushort* gG[2]; const ushort* gU[2];
  ushort* lA[2]; ushort* lG[2]; ushort* lU[2];
#pragma unroll
  for (int p = 0; p < 2; ++p) {
    int seg = p * 8 + wid;
    int flat = seg * 64 + lane;
    int row = flat >> 3, sl = flat & 7;
    int gc = ((sl ^ (row & 7)) << 3);
    gA[p] = A  + (size_t)(bm + row) * K + gc;
    gG[p] = Gt + (size_t)(bn + row) * K + gc;
    gU[p] = Ut + (size_t)(bn + row) * K + gc;
    lA[p] = smem + seg * 512;
    lG[p] = smem + 8192 + seg * 512;
    lU[p] = smem + 16384 + seg * 512;
  }

  f32x4 ag[4][2], au[4][2];
#pragma unroll
  for (int m = 0; m < 4; ++m)
#pragma unroll
    for (int n = 0; n < 2; ++n) {
      ag[m][n] = (f32x4){0.f, 0.f, 0.f, 0.f};
      au[m][n] = (f32x4){0.f, 0.f, 0.f, 0.f};
    }

  int nk = K >> 6;
  for (int kt = 0; kt < nk; ++kt) {
    __syncthreads();
#pragma unroll
    for (int p = 0; p < 2; ++p) {
      gload16(gA[p], lA[p]);
      gload16(gG[p], lG[p]);
      gload16(gU[p], lU[p]);
      gA[p] += 64; gG[p] += 64; gU[p] += 64;
    }
    __syncthreads();
#pragma unroll
    for (int kk = 0; kk < 2; ++kk) {
      int tslot = ((kk * 4 + l4) ^ swz) << 4;
      short8 a[4], bg[2], bu[2];
#pragma unroll
      for (int i = 0; i < 4; ++i)
        a[i] = *(const short8*)(Au + (wr * 64 + i * 16 + l15) * 128 + tslot);
#pragma unroll
      for (int n = 0; n < 2; ++n) {
        int brow = wc * 32 + n * 16 + l15;
        bg[n] = *(const short8*)(Gu + brow * 128 + tslot);
        bu[n] = *(const short8*)(Uu + brow * 128 + tslot);
      }
#pragma unroll
      for (int m = 0; m < 4; ++m)
#pragma unroll
        for (int n = 0; n < 2; ++n) {
          ag[m][n] = __builtin_amdgcn_mfma_f32_16x16x32_bf16(a[m], bg[n], ag[m][n], 0, 0, 0);
          au[m][n] = __builtin_amdgcn_mfma_f32_16x16x32_bf16(a[m], bu[n], au[m][n], 0, 0, 0);
        }
    }
  }

  __syncthreads();
  ushort* Es = smem;
#pragma unroll
  for (int m = 0; m < 4; ++m)
#pragma unroll
    for (int n = 0; n < 2; ++n) {
      int rb0 = wr * 64 + m * 16 + l4 * 4;
      int c   = wc * 32 + n * 16 + l15;
#pragma unroll
      for (int j = 0; j < 4; ++j) {
        float gv = ag[m][n][j];
        float v = gv / (1.f + __expf(-gv)) * au[m][n][j];
        Es[(rb0 + j) * 128 + c] = f2bf(v);
      }
    }
  __syncthreads();
#pragma unroll
  for (int p = 0; p < 4; ++p) {
    int flat = p * 512 + t;              // 0..2047
    int r = flat >> 4, c8 = (flat & 15) * 8;
    *(short8*)(Cb + (size_t)(bm + r) * N + bn + c8) = *(const short8*)&Es[r * 128 + c8];
  }
}

// ---------------- MFMA causal flash attention, k-parity split ----------------
// 512 blocks x 8 waves, (512,4) -> 2 co-resident blocks/CU = 4 waves/SIMD with
// de-correlated barriers. Partial (m, l, O-bf16) dumped to workspace; merged
// by attn_merge_kernel. kh=0 always covers tile 0 -> l0 > 0.
__global__ __launch_bounds__(512, 4) void attn_mfma_kernel(
    const ushort* __restrict__ qkv,   // [B*S][3072] bf16 (Q at 0, K at 1024)
    const ushort* __restrict__ Vt,    // [B*H][64][2048] bf16
    unsigned* __restrict__ PO,        // [16][NT2] packed bf16x2 O-partials
    float* __restrict__ PM, float* __restrict__ PL) {  // [NT2] each
  __shared__ ushort lds[16384];       // 2 x (K 4096 + V 4096)
  const float SL2 = 0.125f * 1.44269504f;   // scale * log2(e)
  int t = threadIdx.x;
  int x = blockIdx.x;
  int lin = ((x & 7) << 6) + (x >> 3);   // XCD chunks of 64 blocks
  int kh = lin & 1;
  int pp = (lin >> 1) & 7;
  int hb = lin >> 4;                     // 0..31
  int h = hb & 15, bb = hb >> 4;
  int lane = t & 63, wv = t >> 6;        // wv 0..7
  int qi = wv >> 2, wsub = wv & 3;
  int qt = qi ? (15 - pp) : pp;
  int q0 = qt * 128;
  int l31 = lane & 31, g = lane >> 5;

  int qrow = q0 + wsub * 32 + l31;
  const ushort* qrow_ptr = qkv + (size_t)(bb * S_ + qrow) * 3072 + h * 64;
  short8 qf[4];
#pragma unroll
  for (int s = 0; s < 4; ++s) qf[s] = *(const short8*)(qrow_ptr + s * 16 + g * 8);

  f32x16 accO[2];
#pragma unroll
  for (int u = 0; u < 2; ++u)
#pragma unroll
    for (int r = 0; r < 16; ++r) accO[u][r] = 0.f;
  float m = -INFINITY, l = 0.f;
  int qg = qrow;
  int qmin = q0 + wsub * 32, qmax = qmin + 31;
  int ntpair = 2 * (16 - pp);            // full staged span of the pair
  int ntk = (ntpair - kh + 1) >> 1;      // this block's tile count (parity kh)

  const ushort* kbase = qkv + (size_t)(bb * S_) * 3072 + 1024 + h * 64;
  const ushort* vbase = Vt + ((size_t)(bb * 16 + h) * 64) * 2048;

  int srow = t >> 3, sslot = t & 7;
  int soff = srow * 64 + ((sslot ^ (srow & 7)) << 3);
  const ushort* kg0 = kbase + (size_t)srow * 3072 + sslot * 8;
  const ushort* vg0 = vbase + (size_t)srow * 2048 + sslot * 8;

  // prologue: stage tile kh into buf 0
  *(short8*)&lds[soff] = *(const short8*)(kg0 + (size_t)kh * (64 * 3072));
  *(short8*)&lds[4096 + soff] = *(const short8*)(vg0 + kh * 64);
  __syncthreads();

  for (int i2 = 0; i2 < ntk; ++i2) {
    int cur = i2 & 1;
    int kti = 2 * i2 + kh;
    int kt = kti << 6;
    bool pf = (i2 + 1 < ntk);
    short8 rk, rv;
    if (pf) {                            // issue next-parity-tile loads early
      rk = *(const short8*)(kg0 + (size_t)(kti + 2) * (64 * 3072));
      rv = *(const short8*)(vg0 + (kti + 2) * 64);
    }
    if (kt <= qmax) {
      const ushort* Kb = lds + cur * 8192;
      const ushort* Vb = Kb + 4096;

      f32x16 accT[2];
#pragma unroll
      for (int t2 = 0; t2 < 2; ++t2)
#pragma unroll
        for (int r = 0; r < 16; ++r) accT[t2][r] = 0.f;
      __builtin_amdgcn_s_setprio(1);
#pragma unroll
      for (int t2 = 0; t2 < 2; ++t2) {
        int key = 32 * t2 + l31;
#pragma unroll
        for (int s = 0; s < 4; ++s) {
          short8 kf = *(const short8*)&Kb[key * 64 + (((2 * s + g) ^ (key & 7)) << 3)];
          accT[t2] = __builtin_amdgcn_mfma_f32_32x32x16_bf16(kf, qf[s], accT[t2], 0, 0, 0);
        }
      }
      __builtin_amdgcn_s_setprio(0);

      bool need_mask = (kt + 63 > qmin);
      float p_[2][16];
      float pmax = -INFINITY;
#pragma unroll
      for (int t2 = 0; t2 < 2; ++t2)
#pragma unroll
        for (int r = 0; r < 16; ++r) {
          float v = accT[t2][r] * SL2;
          if (need_mask) {
            int key = kt + 32 * t2 + (r & 3) + 8 * (r >> 2) + 4 * g;
            if (key > qg) v = -INFINITY;
          }
          p_[t2][r] = v;
          pmax = fmaxf(pmax, v);
        }
      {
        v2i pm = swap32(__float_as_int(pmax), __float_as_int(pmax));
        pmax = fmaxf(pmax, __int_as_float(g ? pm.x : pm.y));
      }

      if (__any(pmax > m + 11.5f)) {     // defer-max
        float mnew = fmaxf(m, pmax);
        float corr = exp2f(m - mnew);
        m = mnew;
        l *= corr;
        float cr[16];
#pragma unroll
        for (int r = 0; r < 16; ++r) cr[r] = __shfl(corr, (r & 3) + 8 * (r >> 2) + 4 * g);
#pragma unroll
        for (int r = 0; r < 16; ++r) { accO[0][r] *= cr[r]; accO[1][r] *= cr[r]; }
      }
      float psum = 0.f;
#pragma unroll
      for (int t2 = 0; t2 < 2; ++t2)
#pragma unroll
        for (int r = 0; r < 16; ++r) {
          float e = exp2f(p_[t2][r] - m);
          p_[t2][r] = e;
          psum += e;
        }
      {
        v2i ps = swap32(__float_as_int(psum), __float_as_int(psum));
        psum += __int_as_float(g ? ps.x : ps.y);
      }
      l += psum;

#pragma unroll
      for (int s = 0; s < 4; ++s) {
        int ca = 2 * s, cb2 = 2 * s + 1;
        int ta = ca >> 2, ra = (ca & 3) * 4;
        int tb = cb2 >> 2, rbq = (cb2 & 3) * 4;
        int w0a = (int)pk2(p_[ta][ra], p_[ta][ra + 1]);
        int w1a = (int)pk2(p_[ta][ra + 2], p_[ta][ra + 3]);
        int w0b = (int)pk2(p_[tb][rbq], p_[tb][rbq + 1]);
        int w1b = (int)pk2(p_[tb][rbq + 2], p_[tb][rbq + 3]);
        v2i r0 = swap32(w0a, w0b);
        v2i r1 = swap32(w1a, w1b);
        union { int u[4]; short8 s8; } pa;
        pa.u[0] = r0.x;
        pa.u[1] = r1.x;
        pa.u[2] = r0.y;
        pa.u[3] = r1.y;
        __builtin_amdgcn_s_setprio(1);
#pragma unroll
        for (int u = 0; u < 2; ++u) {
          int d = 32 * u + l31;
          short8 vf = *(const short8*)&Vb[d * 64 + (((2 * s + g) ^ (d & 7)) << 3)];
          accO[u] = __builtin_amdgcn_mfma_f32_32x32x16_bf16(pa.s8, vf, accO[u], 0, 0, 0);
        }
        __builtin_amdgcn_s_setprio(0);
      }
    }
    if (pf) {                            // write prefetched tile into other buffer
      ushort* dst = lds + (cur ^ 1) * 8192;
      *(short8*)&dst[soff] = rk;
      *(short8*)&dst[4096 + soff] = rv;
    }
    __syncthreads();
  }

  // dump partials (coalesced SoA; O as packed bf16 pairs)
  size_t base = (size_t)lin * 512 + t;
#pragma unroll
  for (int r = 0; r < 16; ++r)
    PO[(size_t)r * NT2_ + base] = pk2(accO[0][r], accO[1][r]);
  PM[base] = m;
  PL[base] = l;
}

// ---------------- attention partial merge (kh=0 + kh=1) ----------------
__global__ __launch_bounds__(512, 2) void attn_merge_kernel(
    const unsigned* __restrict__ PO, const float* __restrict__ PM,
    const float* __restrict__ PL, ushort* __restrict__ AO) {
  __shared__ ushort lds[16384];
  int t = threadIdx.x;
  int xb = blockIdx.x;
  int lin2 = ((xb & 7) << 5) + (xb >> 3);   // XCD chunks of 32
  int pp = lin2 & 7;
  int hb = lin2 >> 3;
  int h = hb & 15, bb = hb >> 4;
  int lane = t & 63, wv = t >> 6;
  int l31 = lane & 31, g = lane >> 5;

  size_t p0 = ((size_t)((hb << 4) | (pp << 1)) * 512) + t;
  size_t p1 = p0 + 512;
  float m0 = PM[p0], l0 = PL[p0];
  float m1 = PM[p1], l1 = PL[p1];
  float mn = fmaxf(m0, m1);
  float c0 = exp2f(m0 - mn), c1 = exp2f(m1 - mn);   // m1=-inf -> c1=0
  float linv = 1.f / (l0 * c0 + l1 * c1);

  float cr0[16], cr1[16], lr[16];
#pragma unroll
  for (int r = 0; r < 16; ++r) {
    int src = (r & 3) + 8 * (r >> 2) + 4 * g;
    cr0[r] = __shfl(c0, src);
    cr1[r] = __shfl(c1, src);
    lr[r]  = __shfl(linv, src);
  }
#pragma unroll
  for (int r = 0; r < 16; ++r) {
    unsigned u0 = PO[(size_t)r * NT2_ + p0];
    unsigned u1 = PO[(size_t)r * NT2_ + p1];
    float a0 = bf2f((ushort)(u0 & 0xffff)), b0 = bf2f((ushort)(u0 >> 16));
    float a1 = bf2f((ushort)(u1 & 0xffff)), b1 = bf2f((ushort)(u1 >> 16));
    int row = wv * 32 + (r & 3) + 8 * (r >> 2) + 4 * g;
    lds[row * 64 + l31]      = f2bf((a0 * cr0[r] + a1 * cr1[r]) * lr[r]);
    lds[row * 64 + 32 + l31] = f2bf((b0 * cr0[r] + b1 * cr1[r]) * lr[r]);
  }
  __syncthreads();
#pragma unroll
  for (int p = 0; p < 4; ++p) {
    int flat = p * 512 + t;              // 0..2047
    int row = flat >> 3, slot = flat & 7;
    int qto = (row < 128) ? pp : (15 - pp);
    int grow = row & 127;
    *(short8*)(AO + (size_t)(bb * S_ + qto * 128 + grow) * 1024 + h * 64 + slot * 8) =
        *(const short8*)&lds[row * 64 + slot * 8];
  }
}

// ---------------- column mean over S (stage 1) ----------------
__global__ void colmean1(const float* __restrict__ X, float* __restrict__ part) {
  int d = blockIdx.x * 256 + threadIdx.x;
  int b = blockIdx.y;
  int ch = blockIdx.z;
  float s = 0.f;
  int s0 = ch * (S_ / 16);
  for (int i = 0; i < S_ / 16; ++i)
    s += X[(size_t)(b * S_ + s0 + i) * D_ + d];
  part[(b * 16 + ch) * D_ + d] = s;
}

// ---------------- colmean stage 2 + recurrent state update (fused, 1 block) ----------------
__global__ __launch_bounds__(1024) void colmean2_state_kernel(
    const float* __restrict__ part, const float* __restrict__ state,
    const float* __restrict__ w_h2s, const float* __restrict__ w_sg,
    float* __restrict__ out_tail) {
  __shared__ float cms[2048];
  __shared__ float nis[128];
  int t = threadIdx.x;
#pragma unroll
  for (int i = 0; i < 2; ++i) {
    int idx = i * 1024 + t;              // 0..2047 = b*D + d
    int b = idx >> 10, d = idx & 1023;
    float s = 0.f;
#pragma unroll
    for (int c = 0; c < 16; ++c) s += part[(b * 16 + c) * D_ + d];
    cms[idx] = s * (1.f / (float)S_);
  }
  __syncthreads();
  {
    int out = t >> 3, ks = t & 7;
    int b = out >> 6, j = out & 63;
    float ni = 0.f;
    int k0 = ks * 128;
#pragma unroll 8
    for (int k = k0; k < k0 + 128; ++k)
      ni += cms[b * 1024 + k] * w_h2s[k * SD_ + j];
    ni += __shfl_xor(ni, 1);
    ni += __shfl_xor(ni, 2);
    ni += __shfl_xor(ni, 4);
    if (ks == 0) nis[out] = ni;
  }
  __syncthreads();
  if (t < 128) {
    int b = t >> 6, j = t & 63;
    float nv = nis[t];
    float g = 0.f;
#pragma unroll
    for (int k = 0; k < SD_; ++k) g += state[b * SD_ + k] * w_sg[k * SD_ + j];
#pragma unroll
    for (int k = 0; k < SD_; ++k) g += nis[b * SD_ + k] * w_sg[(SD_ + k) * SD_ + j];
    g = 1.f / (1.f + __expf(-g));
    float st = state[b * SD_ + j];
    out_tail[t] = st * (1.f - g) + nv * g;
  }
}

extern "C" void kernel_launch(void* const* d_in, const int* in_sizes, int n_in,
                              void* d_out, int out_size, void* d_ws, size_t ws_size,
                              hipStream_t stream) {
  const float* x      = (const float*)d_in[0];
  const float* gamma  = (const float*)d_in[1];
  const float* beta   = (const float*)d_in[2];
  const float* state  = (const float*)d_in[3];
  const float* w_qkv  = (const float*)d_in[4];
  const float* w_o    = (const float*)d_in[5];
  const float* w_gate = (const float*)d_in[6];
  const float* w_up   = (const float*)d_in[7];
  const float* w_down = (const float*)d_in[8];
  const float* norm1w = (const float*)d_in[9];
  const float* norm2w = (const float*)d_in[10];
  const float* w_sm   = (const float*)d_in[11];
  const float* w_h2s  = (const float*)d_in[12];
  const float* w_sg   = (const float*)d_in[13];
  float* out = (float*)d_out;

  float* ws = (float*)d_ws;
  // ws layout (float units). h_bf/wT/wT2 are DEAD during attention -> the
  // 20MB span doubles as the attention partial buffer (18.87MB needed).
  float*  fg     = ws;                          // 2048
  float*  fb     = ws + 2048;                   // 2048
  float*  part   = ws + 8192;                   // 32768
  ushort* h_bf   = (ushort*)(ws + 65536);                    // 2097152 fl (8MB)
  ushort* wT     = (ushort*)(ws + 65536 + 2097152);          // 1572864 fl (6MB)
  ushort* wT2    = (ushort*)(ws + 65536 + 3670016);          // 1572864 fl (6MB)
  unsigned* PO   = (unsigned*)(ws + 65536);                  // 16*NT2 uints (16MB)
  float*  PM     = ws + 65536 + 4194304;                     // NT2 fl (1MB)
  float*  PL     = ws + 65536 + 4456448;                     // NT2 fl (1MB)
  ushort* AO_bf  = (ushort*)(ws + 65536 + 5242880);          // 2097152 fl (8MB)
  ushort* qkv_bf = (ushort*)(ws + 65536 + 7340032);          // 6291456 fl (24MB)
  ushort* Vt_g   = (ushort*)(ws + 65536 + 13631488);         // 2097152 fl (8MB)
  ushort* gu_bf  = qkv_bf;   // reuses qkv slot (dead after attention)

  // 1. FiLM params
  film_kernel<<<dim3(8, B_), 256, 0, stream>>>(state, w_sm, gamma, beta, fg, fb);
  // 2. h = rmsnorm(x,norm1)*fg + fb  -> bf16
  rmsnorm_film_kernel<<<M_, 256, 0, stream>>>(x, norm1w, fg, fb, h_bf);
  // 3. qkv = h @ w_qkv  -> Q/K bf16 + V transposed
  transpose_bf16<<<dim3(D3_ / 32, D_ / 32), 256, 0, stream>>>(w_qkv, wT, D_, D3_);
  gemm_mfma<4><<<(D3_ / 128) * (M_ / 128), 256, 0, stream>>>(
      h_bf, wT, nullptr, nullptr, qkv_bf, Vt_g, M_, D3_, D_);
  // 4. attention: k-parity split main (512 blocks) + merge (256 blocks)
  attn_mfma_kernel<<<512, 512, 0, stream>>>(qkv_bf, Vt_g, PO, PM, PL);
  attn_merge_kernel<<<256, 512, 0, stream>>>(PO, PM, PL, AO_bf);
  // 5. x1 = x + AO @ w_o -> d_out
  transpose_bf16<<<dim3(D_ / 32, D_ / 32), 256, 0, stream>>>(w_o, wT, D_, D_);
  gemm_mfma<3><<<(D_ / 128) * (M_ / 128), 256, 0, stream>>>(
      AO_bf, wT, x, out, nullptr, nullptr, M_, D_, D_);
  // 6. h2 = rmsnorm(x1,norm2)*fg + fb -> bf16
  rmsnorm_film_kernel<<<M_, 256, 0, stream>>>(out, norm2w, fg, fb, h_bf);
  // 7+8. gu = silu(h2 @ w_gate) * (h2 @ w_up)  (fused dual GEMM, 8-wave blocks)
  transpose_bf16_dual<<<dim3(D3_ / 32, D_ / 32, 2), 256, 0, stream>>>(
      w_gate, wT, w_up, wT2, D_, D3_);
  gemm_dual<<<(D3_ / 128) * (M_ / 128), 512, 0, stream>>>(
      h_bf, wT, wT2, gu_bf, M_, D3_, D_);
  // 9. x2 = x1 + gu @ w_down -> d_out
  transpose_bf16<<<dim3(D_ / 32, D3_ / 32), 256, 0, stream>>>(w_down, wT, D3_, D_);
  gemm_mfma<3><<<(D_ / 128) * (M_ / 128), 256, 0, stream>>>(
      gu_bf, wT, out, out, nullptr, nullptr, M_, D_, D3_);
  // 10. column mean + state update (parallel fused tail)
  colmean1<<<dim3(4, B_, 16), 256, 0, stream>>>(out, part);
  colmean2_state_kernel<<<1, 1024, 0, stream>>>(part, state, w_h2s, w_sg,
                                                out + (size_t)M_ * D_);
}